// Round 1
// baseline (1530.942 us; speedup 1.0000x reference)
//
#include <hip/hip_runtime.h>
#include <math.h>

#define NN 50000
#define NE 800000
#define FIN 128
#define FOUT 256
#define EPSF 1e-5f
#define NCHUNK 196  // ceil(NN/256)

// ---------------------------------------------------------------------------
// K1: edge MLP. block=256 handles 64 edges. xd tile + combined w1 (64 cols) in
// LDS; 4x4 micro-tile GEMM [64 edges]x[128]x[64 cols]; epilogue relu+dot(w2)+
// sigmoid with 16-lane shfl reduction. Cols assigned c = tx + 16*j so the
// XOR-swizzled w1t reads are ~conflict-free.
// ---------------------------------------------------------------------------
__global__ __launch_bounds__(256) void edge_mlp_kernel(
    const float* __restrict__ x, const int* __restrict__ rowi, const int* __restrict__ coli,
    const float* __restrict__ w1a, const float* __restrict__ b1a,
    const float* __restrict__ w2a, const float* __restrict__ b2a,
    const float* __restrict__ w1b, const float* __restrict__ b1b,
    const float* __restrict__ w2b, const float* __restrict__ b2b,
    float* __restrict__ v1out, float* __restrict__ v2out)
{
    __shared__ float w1t[64 * 128];   // [c][swizzled k], 32KB
    __shared__ float xd[64][68];      // 64 edges x 64-k phase (+4 pad), 17KB
    int t = threadIdx.x;

    for (int idx = t; idx < 64 * 128; idx += 256) {
        int c = idx >> 7, k = idx & 127;
        float w = (c < 32) ? w1a[k * 32 + c] : w1b[k * 32 + (c - 32)];
        int slot = (k >> 2) ^ (c & 7);
        w1t[c * 128 + (slot << 2) + (k & 3)] = w;
    }

    int e0 = blockIdx.x * 64;
    int tx = t & 15, ty = t >> 4;
    int s = t >> 2, q = t & 3;  // xd loader: edge s, 16-feat quarter q
    int er = rowi[e0 + s], ec = coli[e0 + s];
    const float* xr = x + (size_t)er * FIN;
    const float* xc = x + (size_t)ec * FIN;

    float acc[4][4] = {};  // [edge i][col j], col c = tx + 16*j

    for (int ph = 0; ph < 2; ph++) {
        int kbase = ph * 64;
#pragma unroll
        for (int u = 0; u < 4; u++) {
            int k = q * 16 + u * 4;
            float4 a = *(const float4*)(xr + kbase + k);
            float4 b = *(const float4*)(xc + kbase + k);
            xd[s][k + 0] = fabsf(a.x - b.x);
            xd[s][k + 1] = fabsf(a.y - b.y);
            xd[s][k + 2] = fabsf(a.z - b.z);
            xd[s][k + 3] = fabsf(a.w - b.w);
        }
        __syncthreads();
#pragma unroll
        for (int k = 0; k < 64; k += 4) {
            float4 a4[4], b4[4];
#pragma unroll
            for (int i = 0; i < 4; i++) a4[i] = *(const float4*)&xd[ty * 4 + i][k];
            int kg = kbase + k;
#pragma unroll
            for (int j = 0; j < 4; j++) {
                int c = tx + 16 * j;
                int slot = (kg >> 2) ^ (c & 7);
                b4[j] = *(const float4*)&w1t[c * 128 + (slot << 2)];
            }
#pragma unroll
            for (int i = 0; i < 4; i++)
#pragma unroll
                for (int j = 0; j < 4; j++)
                    acc[i][j] += a4[i].x * b4[j].x + a4[i].y * b4[j].y +
                                 a4[i].z * b4[j].z + a4[i].w * b4[j].w;
        }
        __syncthreads();
    }

    float p1[4] = {0, 0, 0, 0}, p2[4] = {0, 0, 0, 0};
#pragma unroll
    for (int j = 0; j < 4; j++) {
        int c = tx + 16 * j;
        float bb = (c < 32) ? b1a[c] : b1b[c - 32];
        float ww = (c < 32) ? w2a[c] : w2b[c - 32];
#pragma unroll
        for (int i = 0; i < 4; i++) {
            float h = fmaxf(acc[i][j] + bb, 0.f);
            if (j < 2) p1[i] += h * ww; else p2[i] += h * ww;
        }
    }
#pragma unroll
    for (int off = 1; off < 16; off <<= 1)
#pragma unroll
        for (int i = 0; i < 4; i++) {
            p1[i] += __shfl_xor(p1[i], off, 64);
            p2[i] += __shfl_xor(p2[i], off, 64);
        }
    if (tx == 0) {
        float ba = b2a[0], bb2 = b2b[0];
#pragma unroll
        for (int i = 0; i < 4; i++) {
            int e = e0 + ty * 4 + i;
            v1out[e] = 1.f / (1.f + expf(-(p1[i] + ba)));
            v2out[e] = 1.f / (1.f + expf(-(p2[i] + bb2)));
        }
    }
}

// ---------------------------------------------------------------------------
// CSR build: histogram, 3-kernel exclusive scan, fill (packed col/v1/v2).
// ---------------------------------------------------------------------------
__global__ void hist_kernel(const int* __restrict__ rowi, int* __restrict__ counts) {
    int e = blockIdx.x * 256 + threadIdx.x;
    if (e < NE) atomicAdd(&counts[rowi[e]], 1);
}

__global__ void scan1_kernel(const int* __restrict__ counts, int* __restrict__ blksum) {
    __shared__ int s[256];
    int t = threadIdx.x, idx = blockIdx.x * 256 + t;
    s[t] = (idx < NN) ? counts[idx] : 0;
    __syncthreads();
    for (int off = 128; off > 0; off >>= 1) {
        if (t < off) s[t] += s[t + off];
        __syncthreads();
    }
    if (t == 0) blksum[blockIdx.x] = s[0];
}

__global__ void scan2_kernel(const int* __restrict__ blksum, int* __restrict__ blkoff) {
    __shared__ int s[256];
    int t = threadIdx.x;
    int v = (t < NCHUNK) ? blksum[t] : 0;
    s[t] = v; __syncthreads();
    for (int off = 1; off < 256; off <<= 1) {
        int xv = (t >= off) ? s[t - off] : 0;
        __syncthreads();
        s[t] += xv;
        __syncthreads();
    }
    if (t < NCHUNK) blkoff[t] = s[t] - v;  // exclusive
}

__global__ void scan3_kernel(const int* __restrict__ counts, const int* __restrict__ blkoff,
                             int* __restrict__ row_start) {
    __shared__ int s[256];
    int t = threadIdx.x, idx = blockIdx.x * 256 + t;
    int v = (idx < NN) ? counts[idx] : 0;
    s[t] = v; __syncthreads();
    for (int off = 1; off < 256; off <<= 1) {
        int xv = (t >= off) ? s[t - off] : 0;
        __syncthreads();
        s[t] += xv;
        __syncthreads();
    }
    if (idx <= NN) row_start[idx] = s[t] - v + blkoff[blockIdx.x];
}

__global__ void fill_kernel(const int* __restrict__ rowi, const int* __restrict__ coli,
                            const float* __restrict__ v1, const float* __restrict__ v2,
                            const int* __restrict__ row_start, int* __restrict__ cursor,
                            float4* __restrict__ perm) {
    int e = blockIdx.x * 256 + threadIdx.x;
    if (e >= NE) return;
    int r = rowi[e];
    int p = row_start[r] + atomicAdd(&cursor[r], 1);
    float4 qv;
    qv.x = __int_as_float(coli[e]);
    qv.y = v1[e];
    qv.z = v2[e];
    qv.w = 0.f;
    perm[p] = qv;
}

// ---------------------------------------------------------------------------
// spmm: one wave per node, features distributed across lanes, acc in regs.
// ---------------------------------------------------------------------------
__global__ __launch_bounds__(256) void spmm1_kernel(
    const float* __restrict__ x, const float* __restrict__ wid,
    const int* __restrict__ row_start, const float4* __restrict__ perm,
    float* __restrict__ agg)
{
    int lane = threadIdx.x & 63;
    int i = blockIdx.x * 4 + (threadIdx.x >> 6);
    if (i >= NN) return;
    int f0 = lane * 2;
    float a1x = 0, a1y = 0, a2x = 0, a2y = 0;
    int p0 = row_start[i], p1 = row_start[i + 1];
    for (int p = p0; p < p1; p++) {
        float4 pr = perm[p];
        int c = __float_as_int(pr.x);
        float2 f = *(const float2*)(x + (size_t)c * FIN + f0);
        a1x += pr.y * f.x; a1y += pr.y * f.y;
        a2x += pr.z * f.x; a2y += pr.z * f.y;
    }
    float w = wid[i];
    float2 xi = *(const float2*)(x + (size_t)i * FIN + f0);
    float* ag = agg + (size_t)i * 384;
    *(float2*)(ag + f0) = make_float2(w * xi.x, w * xi.y);
    *(float2*)(ag + FIN + f0) = make_float2(a1x, a1y);
    *(float2*)(ag + 2 * FIN + f0) = make_float2(a2x, a2y);
}

__global__ __launch_bounds__(256) void spmm2_kernel(
    const float* __restrict__ h, const float* __restrict__ wid,
    const int* __restrict__ row_start, const float4* __restrict__ perm,
    float* __restrict__ agg)
{
    int lane = threadIdx.x & 63;
    int i = blockIdx.x * 4 + (threadIdx.x >> 6);
    if (i >= NN) return;
    int f0 = lane * 4;
    float4 s1 = {0, 0, 0, 0}, s2 = {0, 0, 0, 0};
    int p0 = row_start[i], p1 = row_start[i + 1];
    for (int p = p0; p < p1; p++) {
        float4 pr = perm[p];
        int c = __float_as_int(pr.x);
        float4 f = *(const float4*)(h + (size_t)c * FOUT + f0);
        s1.x += pr.y * f.x; s1.y += pr.y * f.y; s1.z += pr.y * f.z; s1.w += pr.y * f.w;
        s2.x += pr.z * f.x; s2.y += pr.z * f.y; s2.z += pr.z * f.z; s2.w += pr.z * f.w;
    }
    float w = wid[i];
    float4 hi = *(const float4*)(h + (size_t)i * FOUT + f0);
    float* ag = agg + (size_t)i * 768;
    *(float4*)(ag + f0) = make_float4(w * hi.x, w * hi.y, w * hi.z, w * hi.w);
    *(float4*)(ag + FOUT + f0) = s1;
    *(float4*)(ag + 2 * FOUT + f0) = s2;
}

// ---------------------------------------------------------------------------
// fp32 tiled GEMM: C[M,Ncol] = A[M,K] @ B[K,Ncol] (+bias) (+BN col stats).
// BM=128 BN=64 BK=16, 256 threads, 8x4 micro-tile, A staged transposed in LDS.
// ---------------------------------------------------------------------------
#define BM 128
#define BN 64
#define BK 16
__global__ __launch_bounds__(256) void gemm_kernel(
    const float* __restrict__ A, const float* __restrict__ B,
    const float* __restrict__ bias, float* __restrict__ C,
    int M, int K, int Ncol,
    float* __restrict__ colsum, float* __restrict__ colsq)
{
    __shared__ float At[BK][BM + 4];
    __shared__ float Bs[BK][BN];
    __shared__ float lsum[BN], lsq[BN];
    int t = threadIdx.x;
    int m0 = blockIdx.x * BM;
    int n0 = blockIdx.y * BN;
    int tr = t >> 4, tc = t & 15;
    float acc[8][4] = {};

    for (int k0 = 0; k0 < K; k0 += BK) {
#pragma unroll
        for (int u = 0; u < 2; u++) {
            int fidx = t * 2 + u;
            int mrow = fidx >> 2;
            int kq = (fidx & 3) * 4;
            int gm = m0 + mrow;
            float4 a = (gm < M) ? *(const float4*)(A + (size_t)gm * K + k0 + kq)
                                : make_float4(0, 0, 0, 0);
            At[kq + 0][mrow] = a.x;
            At[kq + 1][mrow] = a.y;
            At[kq + 2][mrow] = a.z;
            At[kq + 3][mrow] = a.w;
        }
        {
            int kk = t >> 4;
            int nn = (t & 15) * 4;
            *(float4*)&Bs[kk][nn] = *(const float4*)(B + (size_t)(k0 + kk) * Ncol + n0 + nn);
        }
        __syncthreads();
#pragma unroll
        for (int k = 0; k < BK; k++) {
            float4 a0 = *(const float4*)&At[k][tr * 8];
            float4 a1 = *(const float4*)&At[k][tr * 8 + 4];
            float4 b0 = *(const float4*)&Bs[k][tc * 4];
            float ar[8] = {a0.x, a0.y, a0.z, a0.w, a1.x, a1.y, a1.z, a1.w};
            float br[4] = {b0.x, b0.y, b0.z, b0.w};
#pragma unroll
            for (int i = 0; i < 8; i++)
#pragma unroll
                for (int j = 0; j < 4; j++) acc[i][j] += ar[i] * br[j];
        }
        __syncthreads();
    }

    float bj[4] = {0, 0, 0, 0};
    if (bias) {
        float4 b4 = *(const float4*)(bias + n0 + tc * 4);
        bj[0] = b4.x; bj[1] = b4.y; bj[2] = b4.z; bj[3] = b4.w;
    }
    float psum[4] = {0, 0, 0, 0}, psq[4] = {0, 0, 0, 0};
#pragma unroll
    for (int i = 0; i < 8; i++) {
        int gm = m0 + tr * 8 + i;
        if (gm < M) {
            float4 o;
            o.x = acc[i][0] + bj[0];
            o.y = acc[i][1] + bj[1];
            o.z = acc[i][2] + bj[2];
            o.w = acc[i][3] + bj[3];
            *(float4*)(C + (size_t)gm * Ncol + n0 + tc * 4) = o;
            if (colsum) {
                psum[0] += o.x; psum[1] += o.y; psum[2] += o.z; psum[3] += o.w;
                psq[0] += o.x * o.x; psq[1] += o.y * o.y; psq[2] += o.z * o.z; psq[3] += o.w * o.w;
            }
        }
    }
    if (colsum) {
        for (int idx = t; idx < BN; idx += 256) { lsum[idx] = 0.f; lsq[idx] = 0.f; }
        __syncthreads();
#pragma unroll
        for (int j = 0; j < 4; j++) {
            atomicAdd(&lsum[tc * 4 + j], psum[j]);
            atomicAdd(&lsq[tc * 4 + j], psq[j]);
        }
        __syncthreads();
        if (t < BN) {
            atomicAdd(&colsum[n0 + t], lsum[t]);
            atomicAdd(&colsq[n0 + t], lsq[t]);
        }
    }
}

// ---------------------------------------------------------------------------
// BN apply (+relu), and final BN+residual+relu.
// stats layout: [0:256)=colsum, [256:512)=colsumsq
// ---------------------------------------------------------------------------
__device__ __forceinline__ float bn1c(float v, float s, float q, float g, float b) {
    const float invn = 1.0f / (float)NN;
    float mu = s * invn;
    float var = q * invn - mu * mu;
    float r = rsqrtf(var + EPSF);
    return (v - mu) * r * g + b;
}

__global__ __launch_bounds__(256) void bn_relu_kernel(
    const float* __restrict__ h, const float* __restrict__ stats,
    const float* __restrict__ g, const float* __restrict__ b, float* __restrict__ o)
{
    size_t idx = (size_t)blockIdx.x * 256 + threadIdx.x;
    int j = ((int)idx & 63) * 4;
    float4 v = ((const float4*)h)[idx];
    float4 r;
    r.x = fmaxf(bn1c(v.x, stats[j + 0], stats[256 + j + 0], g[j + 0], b[j + 0]), 0.f);
    r.y = fmaxf(bn1c(v.y, stats[j + 1], stats[256 + j + 1], g[j + 1], b[j + 1]), 0.f);
    r.z = fmaxf(bn1c(v.z, stats[j + 2], stats[256 + j + 2], g[j + 2], b[j + 2]), 0.f);
    r.w = fmaxf(bn1c(v.w, stats[j + 3], stats[256 + j + 3], g[j + 3], b[j + 3]), 0.f);
    ((float4*)o)[idx] = r;
}

__global__ __launch_bounds__(256) void final_kernel(
    const float* __restrict__ h2, const float* __restrict__ stats,
    const float* __restrict__ g, const float* __restrict__ b,
    const float* __restrict__ resb, float* __restrict__ o)
{
    size_t idx = (size_t)blockIdx.x * 256 + threadIdx.x;
    int j = ((int)idx & 63) * 4;
    float4 v = ((const float4*)h2)[idx];
    float4 rr = ((const float4*)resb)[idx];
    float4 r;
    r.x = fmaxf(bn1c(v.x, stats[j + 0], stats[256 + j + 0], g[j + 0], b[j + 0]) + rr.x, 0.f);
    r.y = fmaxf(bn1c(v.y, stats[j + 1], stats[256 + j + 1], g[j + 1], b[j + 1]) + rr.y, 0.f);
    r.z = fmaxf(bn1c(v.z, stats[j + 2], stats[256 + j + 2], g[j + 2], b[j + 2]) + rr.z, 0.f);
    r.w = fmaxf(bn1c(v.w, stats[j + 3], stats[256 + j + 3], g[j + 3], b[j + 3]) + rr.w, 0.f);
    ((float4*)o)[idx] = r;
}

// ---------------------------------------------------------------------------
extern "C" void kernel_launch(void* const* d_in, const int* in_sizes, int n_in,
                              void* d_out, int out_size, void* d_ws, size_t ws_size,
                              hipStream_t stream)
{
    (void)in_sizes; (void)n_in; (void)out_size; (void)ws_size;
    const float* x    = (const float*)d_in[0];
    const float* wid  = (const float*)d_in[1];
    const int*   widx = (const int*)d_in[2];
    // d_in[3] (win_values) unused by reference
    const float* m1w1 = (const float*)d_in[4];
    const float* m1b1 = (const float*)d_in[5];
    const float* m1w2 = (const float*)d_in[6];
    const float* m1b2 = (const float*)d_in[7];
    const float* m2w1 = (const float*)d_in[8];
    const float* m2b1 = (const float*)d_in[9];
    const float* m2w2 = (const float*)d_in[10];
    const float* m2b2 = (const float*)d_in[11];
    const float* fc1w = (const float*)d_in[12];
    const float* fc1b = (const float*)d_in[13];
    const float* bn1g = (const float*)d_in[14];
    const float* bn1b = (const float*)d_in[15];
    const float* fc2w = (const float*)d_in[16];
    const float* fc2b = (const float*)d_in[17];
    const float* bn2g = (const float*)d_in[18];
    const float* bn2b = (const float*)d_in[19];
    const float* resw = (const float*)d_in[20];
    float* out = (float*)d_out;

    char* ws = (char*)d_ws;
    // Zone A [0, 153.6MB): v1,v2 (dead before agg1) -> agg1 -> h1raw -> agg2 overlay
    float* v1    = (float*)(ws);
    float* v2    = (float*)(ws + (size_t)NE * 4);
    float* agg1  = (float*)(ws);
    float* h1raw = (float*)(ws + (size_t)NN * 384 * 4);
    float* agg2  = (float*)(ws);
    const size_t offB = (size_t)NN * 768 * 4;        // 153,600,000
    // Zone B [153.6MB, 204.8MB): hbn (K5->K6), then h2raw overlay (K7->K9)
    float* hbn   = (float*)(ws + offB);
    float* h2raw = hbn;
    const size_t offC = offB + (size_t)NN * FOUT * 4; // 204,800,000
    // Zone C [204.8MB, 256MB): perm (K2d->K6), then resb overlay (K8->K9)
    float4* perm = (float4*)(ws + offC);
    float*  resb = (float*)(ws + offC);
    const size_t offD = offC + (size_t)NN * FOUT * 4; // 256,000,000
    int* row_start = (int*)(ws + offD);               // (NN+1) ints
    int* cursor    = (int*)(ws + offD + 200064);      // doubles as counts
    int* blksum    = (int*)(ws + offD + 400128);
    int* blkoff    = (int*)(ws + offD + 401152);
    float* stats   = (float*)(ws + offD + 402176);    // 1024 floats: sum1,sq1,sum2,sq2

    dim3 b256(256);

    // 1) edge MLP -> v1, v2
    edge_mlp_kernel<<<NE / 64, b256, 0, stream>>>(x, widx, widx + NE,
        m1w1, m1b1, m1w2, m1b2, m2w1, m2b1, m2w2, m2b2, v1, v2);

    // 2) CSR build
    hipMemsetAsync(cursor, 0, NN * 4, stream);  // counts
    hist_kernel<<<NE / 256, b256, 0, stream>>>(widx, cursor);
    scan1_kernel<<<NCHUNK, b256, 0, stream>>>(cursor, blksum);
    scan2_kernel<<<1, b256, 0, stream>>>(blksum, blkoff);
    scan3_kernel<<<NCHUNK, b256, 0, stream>>>(cursor, blkoff, row_start);
    hipMemsetAsync(cursor, 0, NN * 4, stream);
    fill_kernel<<<NE / 256, b256, 0, stream>>>(widx, widx + NE, v1, v2, row_start, cursor, perm);

    // 3) conv1
    spmm1_kernel<<<NN / 4, b256, 0, stream>>>(x, wid, row_start, perm, agg1);
    hipMemsetAsync(stats, 0, 1024 * 4, stream);
    gemm_kernel<<<dim3((NN + BM - 1) / BM, FOUT / BN), b256, 0, stream>>>(
        agg1, fc1w, fc1b, h1raw, NN, 384, FOUT, stats, stats + 256);
    bn_relu_kernel<<<NN * FOUT / 4 / 256, b256, 0, stream>>>(h1raw, stats, bn1g, bn1b, hbn);

    // 4) conv2 + residual
    spmm2_kernel<<<NN / 4, b256, 0, stream>>>(hbn, wid, row_start, perm, agg2);
    gemm_kernel<<<dim3((NN + BM - 1) / BM, FOUT / BN), b256, 0, stream>>>(
        agg2, fc2w, fc2b, h2raw, NN, 768, FOUT, stats + 512, stats + 768);
    gemm_kernel<<<dim3((NN + BM - 1) / BM, FOUT / BN), b256, 0, stream>>>(
        x, resw, nullptr, resb, NN, FIN, FOUT, nullptr, nullptr);
    final_kernel<<<NN * FOUT / 4 / 256, b256, 0, stream>>>(h2raw, stats + 512, bn2g, bn2b, resb, out);
}

// Round 2
// 994.576 us; speedup vs baseline: 1.5393x; 1.5393x over previous
//
#include <hip/hip_runtime.h>
#include <math.h>

#define NN 50000
#define NE 800000
#define FIN 128
#define FOUT 256
#define EPSF 1e-5f
#define NCHUNK 196  // ceil(NN/256)

typedef __bf16 bf16x8 __attribute__((ext_vector_type(8)));
typedef float f32x4 __attribute__((ext_vector_type(4)));

// ---------------------------------------------------------------------------
// Prep: pack combined edge-MLP weight matrix W1 [128k x 64c] (cols 0..31 =
// mlp1, 32..63 = mlp2) into MFMA B-fragment order, bf16:
//   fragbuf[(kt*4+ct)*64 + lane][i] = W1[kt*32 + (lane>>4)*8 + i][ct*16 + (lane&15)]
// ---------------------------------------------------------------------------
__global__ void prep_w_kernel(const float* __restrict__ w1a, const float* __restrict__ w1b,
                              __bf16* __restrict__ fragbuf)
{
    int idx = blockIdx.x * 256 + threadIdx.x;  // 8192 total
    if (idx >= 8192) return;
    int i = idx & 7, l = (idx >> 3) & 63, ct = (idx >> 9) & 3, kt = idx >> 11;
    int n = l & 15, kb = l >> 4;
    int k = kt * 32 + kb * 8 + i;
    int c = ct * 16 + n;
    float w = (c < 32) ? w1a[k * 32 + c] : w1b[k * 32 + (c - 32)];
    fragbuf[idx] = (__bf16)w;
}

// ---------------------------------------------------------------------------
// Edge MLP via MFMA, zero LDS, no barriers. Each wave: 16 edges per iter.
// A-frag built in-register from per-lane gathers of x[row]/x[col] (lane l =
// edge lane&15, k = (l>>4)*8+i). B-frags (full 128x64 weights) persist in
// 64 VGPRs. Epilogue: relu+dot(w2) per coltile, 16-lane shfl reduce, sigmoid.
// ---------------------------------------------------------------------------
__global__ __launch_bounds__(256) void edge_mlp_mfma(
    const float* __restrict__ x, const int* __restrict__ rowi, const int* __restrict__ coli,
    const __bf16* __restrict__ fragbuf,
    const float* __restrict__ b1a, const float* __restrict__ w2a, const float* __restrict__ b2a,
    const float* __restrict__ b1b, const float* __restrict__ w2b, const float* __restrict__ b2b,
    float* __restrict__ v1out, float* __restrict__ v2out)
{
    int lane = threadIdx.x & 63;
    int gwave = (blockIdx.x * 256 + threadIdx.x) >> 6;
    int nwaves = (gridDim.x * 256) >> 6;

    // persistent B fragments (64 VGPRs)
    bf16x8 bfrag[4][4];
    const bf16x8* fb = (const bf16x8*)fragbuf;
#pragma unroll
    for (int kt = 0; kt < 4; kt++)
#pragma unroll
        for (int ct = 0; ct < 4; ct++)
            bfrag[kt][ct] = fb[(kt * 4 + ct) * 64 + lane];

    int n = lane & 15;   // A-row (edge in group) source col for D, and D col
    int kb = lane >> 4;  // k sub-block / D row group
    float b1c[4], w2c[4];
#pragma unroll
    for (int ct = 0; ct < 4; ct++) {
        int c = ct * 16 + n;
        b1c[ct] = (c < 32) ? b1a[c] : b1b[c - 32];
        w2c[ct] = (c < 32) ? w2a[c] : w2b[c - 32];
    }
    float bias2a = b2a[0], bias2b = b2b[0];

    const int ngroups = NE / 16;  // 50000
    for (int g = gwave; g < ngroups; g += nwaves) {
        int e = g * 16 + n;
        int er = rowi[e], ec = coli[e];
        const float* xr = x + (size_t)er * FIN;
        const float* xc = x + (size_t)ec * FIN;
        f32x4 acc[4] = {{0.f, 0.f, 0.f, 0.f}, {0.f, 0.f, 0.f, 0.f},
                        {0.f, 0.f, 0.f, 0.f}, {0.f, 0.f, 0.f, 0.f}};
#pragma unroll
        for (int kt = 0; kt < 4; kt++) {
            int k0 = kt * 32 + kb * 8;
            float4 a0 = *(const float4*)(xr + k0);
            float4 a1 = *(const float4*)(xr + k0 + 4);
            float4 c0 = *(const float4*)(xc + k0);
            float4 c1 = *(const float4*)(xc + k0 + 4);
            bf16x8 af;
            af[0] = (__bf16)fabsf(a0.x - c0.x);
            af[1] = (__bf16)fabsf(a0.y - c0.y);
            af[2] = (__bf16)fabsf(a0.z - c0.z);
            af[3] = (__bf16)fabsf(a0.w - c0.w);
            af[4] = (__bf16)fabsf(a1.x - c1.x);
            af[5] = (__bf16)fabsf(a1.y - c1.y);
            af[6] = (__bf16)fabsf(a1.z - c1.z);
            af[7] = (__bf16)fabsf(a1.w - c1.w);
#pragma unroll
            for (int ct = 0; ct < 4; ct++)
                acc[ct] = __builtin_amdgcn_mfma_f32_16x16x32_bf16(af, bfrag[kt][ct], acc[ct], 0, 0, 0);
        }
        // D[row=edge (kb*4+r)][col=ct*16+n] in acc[ct][r]
        float p1[4], p2[4];
#pragma unroll
        for (int r = 0; r < 4; r++) {
            float h0 = fmaxf(acc[0][r] + b1c[0], 0.f) * w2c[0];
            float h1 = fmaxf(acc[1][r] + b1c[1], 0.f) * w2c[1];
            float h2 = fmaxf(acc[2][r] + b1c[2], 0.f) * w2c[2];
            float h3 = fmaxf(acc[3][r] + b1c[3], 0.f) * w2c[3];
            p1[r] = h0 + h1;
            p2[r] = h2 + h3;
        }
#pragma unroll
        for (int off = 1; off < 16; off <<= 1)
#pragma unroll
            for (int r = 0; r < 4; r++) {
                p1[r] += __shfl_xor(p1[r], off, 64);
                p2[r] += __shfl_xor(p2[r], off, 64);
            }
        if (n == 0) {
#pragma unroll
            for (int r = 0; r < 4; r++) {
                int eo = g * 16 + kb * 4 + r;
                v1out[eo] = 1.f / (1.f + expf(-(p1[r] + bias2a)));
                v2out[eo] = 1.f / (1.f + expf(-(p2[r] + bias2b)));
            }
        }
    }
}

// ---------------------------------------------------------------------------
// CSR build: histogram, 3-kernel exclusive scan, fill (packed col/v1/v2).
// ---------------------------------------------------------------------------
__global__ void hist_kernel(const int* __restrict__ rowi, int* __restrict__ counts) {
    int e = blockIdx.x * 256 + threadIdx.x;
    if (e < NE) atomicAdd(&counts[rowi[e]], 1);
}

__global__ void scan1_kernel(const int* __restrict__ counts, int* __restrict__ blksum) {
    __shared__ int s[256];
    int t = threadIdx.x, idx = blockIdx.x * 256 + t;
    s[t] = (idx < NN) ? counts[idx] : 0;
    __syncthreads();
    for (int off = 128; off > 0; off >>= 1) {
        if (t < off) s[t] += s[t + off];
        __syncthreads();
    }
    if (t == 0) blksum[blockIdx.x] = s[0];
}

__global__ void scan2_kernel(const int* __restrict__ blksum, int* __restrict__ blkoff) {
    __shared__ int s[256];
    int t = threadIdx.x;
    int v = (t < NCHUNK) ? blksum[t] : 0;
    s[t] = v; __syncthreads();
    for (int off = 1; off < 256; off <<= 1) {
        int xv = (t >= off) ? s[t - off] : 0;
        __syncthreads();
        s[t] += xv;
        __syncthreads();
    }
    if (t < NCHUNK) blkoff[t] = s[t] - v;  // exclusive
}

__global__ void scan3_kernel(const int* __restrict__ counts, const int* __restrict__ blkoff,
                             int* __restrict__ row_start) {
    __shared__ int s[256];
    int t = threadIdx.x, idx = blockIdx.x * 256 + t;
    int v = (idx < NN) ? counts[idx] : 0;
    s[t] = v; __syncthreads();
    for (int off = 1; off < 256; off <<= 1) {
        int xv = (t >= off) ? s[t - off] : 0;
        __syncthreads();
        s[t] += xv;
        __syncthreads();
    }
    if (idx <= NN) row_start[idx] = s[t] - v + blkoff[blockIdx.x];
}

__global__ void fill_kernel(const int* __restrict__ rowi, const int* __restrict__ coli,
                            const float* __restrict__ v1, const float* __restrict__ v2,
                            const int* __restrict__ row_start, int* __restrict__ cursor,
                            float4* __restrict__ perm) {
    int e = blockIdx.x * 256 + threadIdx.x;
    if (e >= NE) return;
    int r = rowi[e];
    int p = row_start[r] + atomicAdd(&cursor[r], 1);
    float4 qv;
    qv.x = __int_as_float(coli[e]);
    qv.y = v1[e];
    qv.z = v2[e];
    qv.w = 0.f;
    perm[p] = qv;
}

// ---------------------------------------------------------------------------
// spmm: one wave per node, features distributed across lanes, acc in regs.
// ---------------------------------------------------------------------------
__global__ __launch_bounds__(256) void spmm1_kernel(
    const float* __restrict__ x, const float* __restrict__ wid,
    const int* __restrict__ row_start, const float4* __restrict__ perm,
    float* __restrict__ agg)
{
    int lane = threadIdx.x & 63;
    int i = blockIdx.x * 4 + (threadIdx.x >> 6);
    if (i >= NN) return;
    int f0 = lane * 2;
    float a1x = 0, a1y = 0, a2x = 0, a2y = 0;
    int p0 = row_start[i], p1 = row_start[i + 1];
    for (int p = p0; p < p1; p++) {
        float4 pr = perm[p];
        int c = __float_as_int(pr.x);
        float2 f = *(const float2*)(x + (size_t)c * FIN + f0);
        a1x += pr.y * f.x; a1y += pr.y * f.y;
        a2x += pr.z * f.x; a2y += pr.z * f.y;
    }
    float w = wid[i];
    float2 xi = *(const float2*)(x + (size_t)i * FIN + f0);
    float* ag = agg + (size_t)i * 384;
    *(float2*)(ag + f0) = make_float2(w * xi.x, w * xi.y);
    *(float2*)(ag + FIN + f0) = make_float2(a1x, a1y);
    *(float2*)(ag + 2 * FIN + f0) = make_float2(a2x, a2y);
}

__global__ __launch_bounds__(256) void spmm2_kernel(
    const float* __restrict__ h, const float* __restrict__ wid,
    const int* __restrict__ row_start, const float4* __restrict__ perm,
    float* __restrict__ agg)
{
    int lane = threadIdx.x & 63;
    int i = blockIdx.x * 4 + (threadIdx.x >> 6);
    if (i >= NN) return;
    int f0 = lane * 4;
    float4 s1 = {0, 0, 0, 0}, s2 = {0, 0, 0, 0};
    int p0 = row_start[i], p1 = row_start[i + 1];
    for (int p = p0; p < p1; p++) {
        float4 pr = perm[p];
        int c = __float_as_int(pr.x);
        float4 f = *(const float4*)(h + (size_t)c * FOUT + f0);
        s1.x += pr.y * f.x; s1.y += pr.y * f.y; s1.z += pr.y * f.z; s1.w += pr.y * f.w;
        s2.x += pr.z * f.x; s2.y += pr.z * f.y; s2.z += pr.z * f.z; s2.w += pr.z * f.w;
    }
    float w = wid[i];
    float4 hi = *(const float4*)(h + (size_t)i * FOUT + f0);
    float* ag = agg + (size_t)i * 768;
    *(float4*)(ag + f0) = make_float4(w * hi.x, w * hi.y, w * hi.z, w * hi.w);
    *(float4*)(ag + FOUT + f0) = s1;
    *(float4*)(ag + 2 * FOUT + f0) = s2;
}

// ---------------------------------------------------------------------------
// fp32 tiled GEMM: C[M,Ncol] = A[M,K] @ B[K,Ncol] (+bias) (+BN col stats).
// BM=128 BN=64 BK=16, 256 threads, 8x4 micro-tile, A staged transposed in LDS.
// ---------------------------------------------------------------------------
#define BM 128
#define BN 64
#define BK 16
__global__ __launch_bounds__(256) void gemm_kernel(
    const float* __restrict__ A, const float* __restrict__ B,
    const float* __restrict__ bias, float* __restrict__ C,
    int M, int K, int Ncol,
    float* __restrict__ colsum, float* __restrict__ colsq)
{
    __shared__ float At[BK][BM + 4];
    __shared__ float Bs[BK][BN];
    __shared__ float lsum[BN], lsq[BN];
    int t = threadIdx.x;
    int m0 = blockIdx.x * BM;
    int n0 = blockIdx.y * BN;
    int tr = t >> 4, tc = t & 15;
    float acc[8][4] = {};

    for (int k0 = 0; k0 < K; k0 += BK) {
#pragma unroll
        for (int u = 0; u < 2; u++) {
            int fidx = t * 2 + u;
            int mrow = fidx >> 2;
            int kq = (fidx & 3) * 4;
            int gm = m0 + mrow;
            float4 a = (gm < M) ? *(const float4*)(A + (size_t)gm * K + k0 + kq)
                                : make_float4(0, 0, 0, 0);
            At[kq + 0][mrow] = a.x;
            At[kq + 1][mrow] = a.y;
            At[kq + 2][mrow] = a.z;
            At[kq + 3][mrow] = a.w;
        }
        {
            int kk = t >> 4;
            int nn = (t & 15) * 4;
            *(float4*)&Bs[kk][nn] = *(const float4*)(B + (size_t)(k0 + kk) * Ncol + n0 + nn);
        }
        __syncthreads();
#pragma unroll
        for (int k = 0; k < BK; k++) {
            float4 a0 = *(const float4*)&At[k][tr * 8];
            float4 a1 = *(const float4*)&At[k][tr * 8 + 4];
            float4 b0 = *(const float4*)&Bs[k][tc * 4];
            float ar[8] = {a0.x, a0.y, a0.z, a0.w, a1.x, a1.y, a1.z, a1.w};
            float br[4] = {b0.x, b0.y, b0.z, b0.w};
#pragma unroll
            for (int i = 0; i < 8; i++)
#pragma unroll
                for (int j = 0; j < 4; j++) acc[i][j] += ar[i] * br[j];
        }
        __syncthreads();
    }

    float bj[4] = {0, 0, 0, 0};
    if (bias) {
        float4 b4 = *(const float4*)(bias + n0 + tc * 4);
        bj[0] = b4.x; bj[1] = b4.y; bj[2] = b4.z; bj[3] = b4.w;
    }
    float psum[4] = {0, 0, 0, 0}, psq[4] = {0, 0, 0, 0};
#pragma unroll
    for (int i = 0; i < 8; i++) {
        int gm = m0 + tr * 8 + i;
        if (gm < M) {
            float4 o;
            o.x = acc[i][0] + bj[0];
            o.y = acc[i][1] + bj[1];
            o.z = acc[i][2] + bj[2];
            o.w = acc[i][3] + bj[3];
            *(float4*)(C + (size_t)gm * Ncol + n0 + tc * 4) = o;
            if (colsum) {
                psum[0] += o.x; psum[1] += o.y; psum[2] += o.z; psum[3] += o.w;
                psq[0] += o.x * o.x; psq[1] += o.y * o.y; psq[2] += o.z * o.z; psq[3] += o.w * o.w;
            }
        }
    }
    if (colsum) {
        for (int idx = t; idx < BN; idx += 256) { lsum[idx] = 0.f; lsq[idx] = 0.f; }
        __syncthreads();
#pragma unroll
        for (int j = 0; j < 4; j++) {
            atomicAdd(&lsum[tc * 4 + j], psum[j]);
            atomicAdd(&lsq[tc * 4 + j], psq[j]);
        }
        __syncthreads();
        if (t < BN) {
            atomicAdd(&colsum[n0 + t], lsum[t]);
            atomicAdd(&colsq[n0 + t], lsq[t]);
        }
    }
}

// ---------------------------------------------------------------------------
// BN apply (+relu), and final BN+residual+relu.
// stats layout: [0:256)=colsum, [256:512)=colsumsq
// ---------------------------------------------------------------------------
__device__ __forceinline__ float bn1c(float v, float s, float q, float g, float b) {
    const float invn = 1.0f / (float)NN;
    float mu = s * invn;
    float var = q * invn - mu * mu;
    float r = rsqrtf(var + EPSF);
    return (v - mu) * r * g + b;
}

__global__ __launch_bounds__(256) void bn_relu_kernel(
    const float* __restrict__ h, const float* __restrict__ stats,
    const float* __restrict__ g, const float* __restrict__ b, float* __restrict__ o)
{
    size_t idx = (size_t)blockIdx.x * 256 + threadIdx.x;
    int j = ((int)idx & 63) * 4;
    float4 v = ((const float4*)h)[idx];
    float4 r;
    r.x = fmaxf(bn1c(v.x, stats[j + 0], stats[256 + j + 0], g[j + 0], b[j + 0]), 0.f);
    r.y = fmaxf(bn1c(v.y, stats[j + 1], stats[256 + j + 1], g[j + 1], b[j + 1]), 0.f);
    r.z = fmaxf(bn1c(v.z, stats[j + 2], stats[256 + j + 2], g[j + 2], b[j + 2]), 0.f);
    r.w = fmaxf(bn1c(v.w, stats[j + 3], stats[256 + j + 3], g[j + 3], b[j + 3]), 0.f);
    ((float4*)o)[idx] = r;
}

__global__ __launch_bounds__(256) void final_kernel(
    const float* __restrict__ h2, const float* __restrict__ stats,
    const float* __restrict__ g, const float* __restrict__ b,
    const float* __restrict__ resb, float* __restrict__ o)
{
    size_t idx = (size_t)blockIdx.x * 256 + threadIdx.x;
    int j = ((int)idx & 63) * 4;
    float4 v = ((const float4*)h2)[idx];
    float4 rr = ((const float4*)resb)[idx];
    float4 r;
    r.x = fmaxf(bn1c(v.x, stats[j + 0], stats[256 + j + 0], g[j + 0], b[j + 0]) + rr.x, 0.f);
    r.y = fmaxf(bn1c(v.y, stats[j + 1], stats[256 + j + 1], g[j + 1], b[j + 1]) + rr.y, 0.f);
    r.z = fmaxf(bn1c(v.z, stats[j + 2], stats[256 + j + 2], g[j + 2], b[j + 2]) + rr.z, 0.f);
    r.w = fmaxf(bn1c(v.w, stats[j + 3], stats[256 + j + 3], g[j + 3], b[j + 3]) + rr.w, 0.f);
    ((float4*)o)[idx] = r;
}

// ---------------------------------------------------------------------------
extern "C" void kernel_launch(void* const* d_in, const int* in_sizes, int n_in,
                              void* d_out, int out_size, void* d_ws, size_t ws_size,
                              hipStream_t stream)
{
    (void)in_sizes; (void)n_in; (void)out_size; (void)ws_size;
    const float* x    = (const float*)d_in[0];
    const float* wid  = (const float*)d_in[1];
    const int*   widx = (const int*)d_in[2];
    // d_in[3] (win_values) unused by reference
    const float* m1w1 = (const float*)d_in[4];
    const float* m1b1 = (const float*)d_in[5];
    const float* m1w2 = (const float*)d_in[6];
    const float* m1b2 = (const float*)d_in[7];
    const float* m2w1 = (const float*)d_in[8];
    const float* m2b1 = (const float*)d_in[9];
    const float* m2w2 = (const float*)d_in[10];
    const float* m2b2 = (const float*)d_in[11];
    const float* fc1w = (const float*)d_in[12];
    const float* fc1b = (const float*)d_in[13];
    const float* bn1g = (const float*)d_in[14];
    const float* bn1b = (const float*)d_in[15];
    const float* fc2w = (const float*)d_in[16];
    const float* fc2b = (const float*)d_in[17];
    const float* bn2g = (const float*)d_in[18];
    const float* bn2b = (const float*)d_in[19];
    const float* resw = (const float*)d_in[20];
    float* out = (float*)d_out;

    char* ws = (char*)d_ws;
    // Zone A [0, 153.6MB): v1,v2 (dead before agg1) -> agg1 -> h1raw -> agg2 overlay
    float* v1    = (float*)(ws);
    float* v2    = (float*)(ws + (size_t)NE * 4);
    float* agg1  = (float*)(ws);
    float* h1raw = (float*)(ws + (size_t)NN * 384 * 4);
    float* agg2  = (float*)(ws);
    const size_t offB = (size_t)NN * 768 * 4;        // 153,600,000
    // Zone B [153.6MB, 204.8MB): hbn (K5->K6), then h2raw overlay (K7->K9)
    float* hbn   = (float*)(ws + offB);
    float* h2raw = hbn;
    const size_t offC = offB + (size_t)NN * FOUT * 4; // 204,800,000
    // Zone C [204.8MB, 256MB): perm (K2d->K6), then resb overlay (K8->K9)
    float4* perm = (float4*)(ws + offC);
    float*  resb = (float*)(ws + offC);
    const size_t offD = offC + (size_t)NN * FOUT * 4; // 256,000,000
    int* row_start = (int*)(ws + offD);               // (NN+1) ints
    int* cursor    = (int*)(ws + offD + 200064);      // doubles as counts
    int* blksum    = (int*)(ws + offD + 400128);
    int* blkoff    = (int*)(ws + offD + 401152);
    float* stats   = (float*)(ws + offD + 402176);    // 1024 floats: sum1,sq1,sum2,sq2
    __bf16* fragbuf = (__bf16*)(ws + offD + 406272);  // 8192 bf16 = 16KB

    dim3 b256(256);

    // 1) edge MLP -> v1, v2  (MFMA, weights packed to fragments first)
    prep_w_kernel<<<32, b256, 0, stream>>>(m1w1, m2w1, fragbuf);
    edge_mlp_mfma<<<1024, b256, 0, stream>>>(x, widx, widx + NE, fragbuf,
        m1b1, m1w2, m1b2, m2b1, m2w2, m2b2, v1, v2);

    // 2) CSR build
    hipMemsetAsync(cursor, 0, NN * 4, stream);  // counts
    hist_kernel<<<NE / 256, b256, 0, stream>>>(widx, cursor);
    scan1_kernel<<<NCHUNK, b256, 0, stream>>>(cursor, blksum);
    scan2_kernel<<<1, b256, 0, stream>>>(blksum, blkoff);
    scan3_kernel<<<NCHUNK, b256, 0, stream>>>(cursor, blkoff, row_start);
    hipMemsetAsync(cursor, 0, NN * 4, stream);
    fill_kernel<<<NE / 256, b256, 0, stream>>>(widx, widx + NE, v1, v2, row_start, cursor, perm);

    // 3) conv1
    spmm1_kernel<<<NN / 4, b256, 0, stream>>>(x, wid, row_start, perm, agg1);
    hipMemsetAsync(stats, 0, 1024 * 4, stream);
    gemm_kernel<<<dim3((NN + BM - 1) / BM, FOUT / BN), b256, 0, stream>>>(
        agg1, fc1w, fc1b, h1raw, NN, 384, FOUT, stats, stats + 256);
    bn_relu_kernel<<<NN * FOUT / 4 / 256, b256, 0, stream>>>(h1raw, stats, bn1g, bn1b, hbn);

    // 4) conv2 + residual
    spmm2_kernel<<<NN / 4, b256, 0, stream>>>(hbn, wid, row_start, perm, agg2);
    gemm_kernel<<<dim3((NN + BM - 1) / BM, FOUT / BN), b256, 0, stream>>>(
        agg2, fc2w, fc2b, h2raw, NN, 768, FOUT, stats + 512, stats + 768);
    gemm_kernel<<<dim3((NN + BM - 1) / BM, FOUT / BN), b256, 0, stream>>>(
        x, resw, nullptr, resb, NN, FIN, FOUT, nullptr, nullptr);
    final_kernel<<<NN * FOUT / 4 / 256, b256, 0, stream>>>(h2raw, stats + 512, bn2g, bn2b, resb, out);
}

// Round 3
// 839.523 us; speedup vs baseline: 1.8236x; 1.1847x over previous
//
#include <hip/hip_runtime.h>
#include <hip/hip_bf16.h>
#include <math.h>

#define NN 50000
#define NE 800000
#define FIN 128
#define FOUT 256
#define EPSF 1e-5f
#define NCHUNK 196  // ceil(NN/256)

typedef __bf16 bf16x8 __attribute__((ext_vector_type(8)));
typedef __bf16 bf16x4 __attribute__((ext_vector_type(4)));
typedef __bf16 bf16x2 __attribute__((ext_vector_type(2)));
typedef float f32x4 __attribute__((ext_vector_type(4)));

// ---------------------------------------------------------------------------
// fp32 -> bf16 convert (8 elems/thread)
// ---------------------------------------------------------------------------
__global__ void cvt_bf16_kernel(const float* __restrict__ in, __bf16* __restrict__ out, int n8) {
    int idx = blockIdx.x * 256 + threadIdx.x;
    if (idx >= n8) return;
    float4 a = ((const float4*)in)[idx * 2 + 0];
    float4 b = ((const float4*)in)[idx * 2 + 1];
    bf16x8 v = {(__bf16)a.x, (__bf16)a.y, (__bf16)a.z, (__bf16)a.w,
                (__bf16)b.x, (__bf16)b.y, (__bf16)b.z, (__bf16)b.w};
    ((bf16x8*)out)[idx] = v;
}

// ---------------------------------------------------------------------------
// Pack dense B [K x 256] fp32 row-major into MFMA B-fragment order bf16:
// frag[((kk*16+ct)*64+l)*8+i] = B[kk*32+(l>>4)*8+i][ct*16+(l&15)]
// ---------------------------------------------------------------------------
__global__ void prep_b_kernel(const float* __restrict__ B, __bf16* __restrict__ frag, int K) {
    int idx = blockIdx.x * 256 + threadIdx.x;
    if (idx >= K * 256) return;
    int i = idx & 7, l = (idx >> 3) & 63, ct = (idx >> 9) & 15, kk = idx >> 13;
    int k = kk * 32 + (l >> 4) * 8 + i;
    int c = ct * 16 + (l & 15);
    frag[idx] = (__bf16)B[k * 256 + c];
}

// ---------------------------------------------------------------------------
// Pack combined edge-MLP weights W1 [128k x 64c] (cols 0..31=mlp1, 32..63=mlp2)
// ---------------------------------------------------------------------------
__global__ void prep_w_kernel(const float* __restrict__ w1a, const float* __restrict__ w1b,
                              __bf16* __restrict__ fragbuf)
{
    int idx = blockIdx.x * 256 + threadIdx.x;  // 8192 total
    if (idx >= 8192) return;
    int i = idx & 7, l = (idx >> 3) & 63, ct = (idx >> 9) & 3, kt = idx >> 11;
    int n = l & 15, kb = l >> 4;
    int k = kt * 32 + kb * 8 + i;
    int c = ct * 16 + n;
    float w = (c < 32) ? w1a[k * 32 + c] : w1b[k * 32 + (c - 32)];
    fragbuf[idx] = (__bf16)w;
}

// ---------------------------------------------------------------------------
// Edge MLP via MFMA, zero LDS, no barriers; x gathered as bf16 (16B/lane/kt).
// ---------------------------------------------------------------------------
__global__ __launch_bounds__(256) void edge_mlp_mfma(
    const __bf16* __restrict__ x, const int* __restrict__ rowi, const int* __restrict__ coli,
    const __bf16* __restrict__ fragbuf,
    const float* __restrict__ b1a, const float* __restrict__ w2a, const float* __restrict__ b2a,
    const float* __restrict__ b1b, const float* __restrict__ w2b, const float* __restrict__ b2b,
    float* __restrict__ v1out, float* __restrict__ v2out)
{
    int lane = threadIdx.x & 63;
    int gwave = (blockIdx.x * 256 + threadIdx.x) >> 6;
    int nwaves = (gridDim.x * 256) >> 6;

    bf16x8 bfrag[4][4];
    const bf16x8* fb = (const bf16x8*)fragbuf;
#pragma unroll
    for (int kt = 0; kt < 4; kt++)
#pragma unroll
        for (int ct = 0; ct < 4; ct++)
            bfrag[kt][ct] = fb[(kt * 4 + ct) * 64 + lane];

    int n = lane & 15;
    int kb = lane >> 4;
    float b1c[4], w2c[4];
#pragma unroll
    for (int ct = 0; ct < 4; ct++) {
        int c = ct * 16 + n;
        b1c[ct] = (c < 32) ? b1a[c] : b1b[c - 32];
        w2c[ct] = (c < 32) ? w2a[c] : w2b[c - 32];
    }
    float bias2a = b2a[0], bias2b = b2b[0];

    const int ngroups = NE / 16;
    for (int g = gwave; g < ngroups; g += nwaves) {
        int e = g * 16 + n;
        int er = rowi[e], ec = coli[e];
        const __bf16* xr = x + (size_t)er * FIN + kb * 8;
        const __bf16* xc = x + (size_t)ec * FIN + kb * 8;
        f32x4 acc[4] = {{0.f, 0.f, 0.f, 0.f}, {0.f, 0.f, 0.f, 0.f},
                        {0.f, 0.f, 0.f, 0.f}, {0.f, 0.f, 0.f, 0.f}};
#pragma unroll
        for (int kt = 0; kt < 4; kt++) {
            bf16x8 a = *(const bf16x8*)(xr + kt * 32);
            bf16x8 c = *(const bf16x8*)(xc + kt * 32);
            bf16x8 af;
#pragma unroll
            for (int i = 0; i < 8; i++)
                af[i] = (__bf16)fabsf((float)a[i] - (float)c[i]);
#pragma unroll
            for (int ct = 0; ct < 4; ct++)
                acc[ct] = __builtin_amdgcn_mfma_f32_16x16x32_bf16(af, bfrag[kt][ct], acc[ct], 0, 0, 0);
        }
        float p1[4], p2[4];
#pragma unroll
        for (int r = 0; r < 4; r++) {
            float h0 = fmaxf(acc[0][r] + b1c[0], 0.f) * w2c[0];
            float h1 = fmaxf(acc[1][r] + b1c[1], 0.f) * w2c[1];
            float h2 = fmaxf(acc[2][r] + b1c[2], 0.f) * w2c[2];
            float h3 = fmaxf(acc[3][r] + b1c[3], 0.f) * w2c[3];
            p1[r] = h0 + h1;
            p2[r] = h2 + h3;
        }
#pragma unroll
        for (int off = 1; off < 16; off <<= 1)
#pragma unroll
            for (int r = 0; r < 4; r++) {
                p1[r] += __shfl_xor(p1[r], off, 64);
                p2[r] += __shfl_xor(p2[r], off, 64);
            }
        if (n == 0) {
#pragma unroll
            for (int r = 0; r < 4; r++) {
                int eo = g * 16 + kb * 4 + r;
                v1out[eo] = 1.f / (1.f + expf(-(p1[r] + bias2a)));
                v2out[eo] = 1.f / (1.f + expf(-(p2[r] + bias2b)));
            }
        }
    }
}

// ---------------------------------------------------------------------------
// CSR build: histogram, 3-kernel exclusive scan, fill (packed col/v1/v2).
// ---------------------------------------------------------------------------
__global__ void hist_kernel(const int* __restrict__ rowi, int* __restrict__ counts) {
    int e = blockIdx.x * 256 + threadIdx.x;
    if (e < NE) atomicAdd(&counts[rowi[e]], 1);
}

__global__ void scan1_kernel(const int* __restrict__ counts, int* __restrict__ blksum) {
    __shared__ int s[256];
    int t = threadIdx.x, idx = blockIdx.x * 256 + t;
    s[t] = (idx < NN) ? counts[idx] : 0;
    __syncthreads();
    for (int off = 128; off > 0; off >>= 1) {
        if (t < off) s[t] += s[t + off];
        __syncthreads();
    }
    if (t == 0) blksum[blockIdx.x] = s[0];
}

__global__ void scan2_kernel(const int* __restrict__ blksum, int* __restrict__ blkoff) {
    __shared__ int s[256];
    int t = threadIdx.x;
    int v = (t < NCHUNK) ? blksum[t] : 0;
    s[t] = v; __syncthreads();
    for (int off = 1; off < 256; off <<= 1) {
        int xv = (t >= off) ? s[t - off] : 0;
        __syncthreads();
        s[t] += xv;
        __syncthreads();
    }
    if (t < NCHUNK) blkoff[t] = s[t] - v;  // exclusive
}

__global__ void scan3_kernel(const int* __restrict__ counts, const int* __restrict__ blkoff,
                             int* __restrict__ row_start) {
    __shared__ int s[256];
    int t = threadIdx.x, idx = blockIdx.x * 256 + t;
    int v = (idx < NN) ? counts[idx] : 0;
    s[t] = v; __syncthreads();
    for (int off = 1; off < 256; off <<= 1) {
        int xv = (t >= off) ? s[t - off] : 0;
        __syncthreads();
        s[t] += xv;
        __syncthreads();
    }
    if (idx <= NN) row_start[idx] = s[t] - v + blkoff[blockIdx.x];
}

__global__ void fill_kernel(const int* __restrict__ rowi, const int* __restrict__ coli,
                            const float* __restrict__ v1, const float* __restrict__ v2,
                            const int* __restrict__ row_start, int* __restrict__ cursor,
                            float4* __restrict__ perm) {
    int e = blockIdx.x * 256 + threadIdx.x;
    if (e >= NE) return;
    int r = rowi[e];
    int p = row_start[r] + atomicAdd(&cursor[r], 1);
    float4 qv;
    qv.x = __int_as_float(coli[e]);
    qv.y = v1[e];
    qv.z = v2[e];
    qv.w = 0.f;
    perm[p] = qv;
}

// ---------------------------------------------------------------------------
// spmm: one wave per node, bf16 gathers, fp32 accumulate, bf16 agg out.
// ---------------------------------------------------------------------------
__global__ __launch_bounds__(256) void spmm1_kernel(
    const __bf16* __restrict__ x, const float* __restrict__ wid,
    const int* __restrict__ row_start, const float4* __restrict__ perm,
    __bf16* __restrict__ agg)
{
    int lane = threadIdx.x & 63;
    int i = blockIdx.x * 4 + (threadIdx.x >> 6);
    if (i >= NN) return;
    int f0 = lane * 2;
    float a1x = 0, a1y = 0, a2x = 0, a2y = 0;
    int p0 = row_start[i], p1 = row_start[i + 1];
    for (int p = p0; p < p1; p++) {
        float4 pr = perm[p];
        int c = __float_as_int(pr.x);
        bf16x2 f = *(const bf16x2*)(x + (size_t)c * FIN + f0);
        float fx = (float)f[0], fy = (float)f[1];
        a1x += pr.y * fx; a1y += pr.y * fy;
        a2x += pr.z * fx; a2y += pr.z * fy;
    }
    float w = wid[i];
    bf16x2 xi = *(const bf16x2*)(x + (size_t)i * FIN + f0);
    __bf16* ag = agg + (size_t)i * 384;
    *(bf16x2*)(ag + f0) = (bf16x2){(__bf16)(w * (float)xi[0]), (__bf16)(w * (float)xi[1])};
    *(bf16x2*)(ag + FIN + f0) = (bf16x2){(__bf16)a1x, (__bf16)a1y};
    *(bf16x2*)(ag + 2 * FIN + f0) = (bf16x2){(__bf16)a2x, (__bf16)a2y};
}

__global__ __launch_bounds__(256) void spmm2_kernel(
    const __bf16* __restrict__ h, const float* __restrict__ wid,
    const int* __restrict__ row_start, const float4* __restrict__ perm,
    __bf16* __restrict__ agg)
{
    int lane = threadIdx.x & 63;
    int i = blockIdx.x * 4 + (threadIdx.x >> 6);
    if (i >= NN) return;
    int f0 = lane * 4;
    float s1x = 0, s1y = 0, s1z = 0, s1w = 0, s2x = 0, s2y = 0, s2z = 0, s2w = 0;
    int p0 = row_start[i], p1 = row_start[i + 1];
    for (int p = p0; p < p1; p++) {
        float4 pr = perm[p];
        int c = __float_as_int(pr.x);
        bf16x4 f = *(const bf16x4*)(h + (size_t)c * FOUT + f0);
        float fx = (float)f[0], fy = (float)f[1], fz = (float)f[2], fw = (float)f[3];
        s1x += pr.y * fx; s1y += pr.y * fy; s1z += pr.y * fz; s1w += pr.y * fw;
        s2x += pr.z * fx; s2y += pr.z * fy; s2z += pr.z * fz; s2w += pr.z * fw;
    }
    float w = wid[i];
    bf16x4 hi = *(const bf16x4*)(h + (size_t)i * FOUT + f0);
    __bf16* ag = agg + (size_t)i * 768;
    *(bf16x4*)(ag + f0) = (bf16x4){(__bf16)(w * (float)hi[0]), (__bf16)(w * (float)hi[1]),
                                   (__bf16)(w * (float)hi[2]), (__bf16)(w * (float)hi[3])};
    *(bf16x4*)(ag + FOUT + f0) = (bf16x4){(__bf16)s1x, (__bf16)s1y, (__bf16)s1z, (__bf16)s1w};
    *(bf16x4*)(ag + 2 * FOUT + f0) = (bf16x4){(__bf16)s2x, (__bf16)s2y, (__bf16)s2z, (__bf16)s2w};
}

// ---------------------------------------------------------------------------
// bf16 MFMA GEMM: C[M,256] = A[M,K]@B[K,256] (+bias) (+BN col stats).
// BM=64, 4 waves; wave w: rows w*16, 16 col-fragments (full N=256).
// Zero LDS in main loop (A-frags gathered, B-frags from packed L2-warm buf).
// ---------------------------------------------------------------------------
#define GBM 64
__global__ __launch_bounds__(256) void gemm_mfma(
    const __bf16* __restrict__ A, const __bf16* __restrict__ Bfrag,
    const float* __restrict__ bias, float* __restrict__ C,
    int M, int K, float* __restrict__ colsum, float* __restrict__ colsq)
{
    __shared__ float lsum[256], lsq[256];
    int t = threadIdx.x, lane = t & 63;
    int w = t >> 6;
    int n = lane & 15, kb = lane >> 4;
    int rowbase = blockIdx.x * GBM + w * 16;
    int arow = rowbase + n;
    if (arow > M - 1) arow = M - 1;
    const __bf16* ap = A + (size_t)arow * K + kb * 8;
    const bf16x8* bp = (const bf16x8*)Bfrag + lane;

    f32x4 acc[16];
#pragma unroll
    for (int ct = 0; ct < 16; ct++) acc[ct] = (f32x4){0.f, 0.f, 0.f, 0.f};

    int nk = K >> 5;
    for (int kk = 0; kk < nk; kk++) {
        bf16x8 af = *(const bf16x8*)(ap + kk * 32);
#pragma unroll
        for (int ct = 0; ct < 16; ct++) {
            bf16x8 bf = bp[(kk * 16 + ct) * 64];
            acc[ct] = __builtin_amdgcn_mfma_f32_16x16x32_bf16(af, bf, acc[ct], 0, 0, 0);
        }
    }

    bool dostats = (colsum != nullptr);
    if (dostats) {
        lsum[t] = 0.f; lsq[t] = 0.f;
        __syncthreads();
    }
    int crow0 = rowbase + kb * 4;
#pragma unroll
    for (int ct = 0; ct < 16; ct++) {
        int col = ct * 16 + n;
        float bv = bias ? bias[col] : 0.f;
        float ps = 0.f, pq = 0.f;
#pragma unroll
        for (int r = 0; r < 4; r++) {
            int gm = crow0 + r;
            if (gm < M) {
                float v = acc[ct][r] + bv;
                C[(size_t)gm * 256 + col] = v;
                ps += v; pq += v * v;
            }
        }
        if (dostats) {
            ps += __shfl_xor(ps, 16, 64); pq += __shfl_xor(pq, 16, 64);
            ps += __shfl_xor(ps, 32, 64); pq += __shfl_xor(pq, 32, 64);
            if (lane < 16) {
                atomicAdd(&lsum[col], ps);
                atomicAdd(&lsq[col], pq);
            }
        }
    }
    if (dostats) {
        __syncthreads();
        atomicAdd(&colsum[t], lsum[t]);
        atomicAdd(&colsq[t], lsq[t]);
    }
}

// ---------------------------------------------------------------------------
// BN apply (+relu) -> bf16, and final BN+residual+relu -> fp32.
// ---------------------------------------------------------------------------
__device__ __forceinline__ float bn1c(float v, float s, float q, float g, float b) {
    const float invn = 1.0f / (float)NN;
    float mu = s * invn;
    float var = q * invn - mu * mu;
    float r = rsqrtf(var + EPSF);
    return (v - mu) * r * g + b;
}

__global__ __launch_bounds__(256) void bn_relu_kernel(
    const float* __restrict__ h, const float* __restrict__ stats,
    const float* __restrict__ g, const float* __restrict__ b, __bf16* __restrict__ o)
{
    size_t idx = (size_t)blockIdx.x * 256 + threadIdx.x;
    int j = ((int)idx & 63) * 4;
    float4 v = ((const float4*)h)[idx];
    bf16x4 r;
    r[0] = (__bf16)fmaxf(bn1c(v.x, stats[j + 0], stats[256 + j + 0], g[j + 0], b[j + 0]), 0.f);
    r[1] = (__bf16)fmaxf(bn1c(v.y, stats[j + 1], stats[256 + j + 1], g[j + 1], b[j + 1]), 0.f);
    r[2] = (__bf16)fmaxf(bn1c(v.z, stats[j + 2], stats[256 + j + 2], g[j + 2], b[j + 2]), 0.f);
    r[3] = (__bf16)fmaxf(bn1c(v.w, stats[j + 3], stats[256 + j + 3], g[j + 3], b[j + 3]), 0.f);
    ((bf16x4*)o)[idx] = r;
}

__global__ __launch_bounds__(256) void final_kernel(
    const float* __restrict__ h2, const float* __restrict__ stats,
    const float* __restrict__ g, const float* __restrict__ b,
    const float* __restrict__ resb, float* __restrict__ o)
{
    size_t idx = (size_t)blockIdx.x * 256 + threadIdx.x;
    int j = ((int)idx & 63) * 4;
    float4 v = ((const float4*)h2)[idx];
    float4 rr = ((const float4*)resb)[idx];
    float4 r;
    r.x = fmaxf(bn1c(v.x, stats[j + 0], stats[256 + j + 0], g[j + 0], b[j + 0]) + rr.x, 0.f);
    r.y = fmaxf(bn1c(v.y, stats[j + 1], stats[256 + j + 1], g[j + 1], b[j + 1]) + rr.y, 0.f);
    r.z = fmaxf(bn1c(v.z, stats[j + 2], stats[256 + j + 2], g[j + 2], b[j + 2]) + rr.z, 0.f);
    r.w = fmaxf(bn1c(v.w, stats[j + 3], stats[256 + j + 3], g[j + 3], b[j + 3]) + rr.w, 0.f);
    ((float4*)o)[idx] = r;
}

// ---------------------------------------------------------------------------
extern "C" void kernel_launch(void* const* d_in, const int* in_sizes, int n_in,
                              void* d_out, int out_size, void* d_ws, size_t ws_size,
                              hipStream_t stream)
{
    (void)in_sizes; (void)n_in; (void)out_size; (void)ws_size;
    const float* x    = (const float*)d_in[0];
    const float* wid  = (const float*)d_in[1];
    const int*   widx = (const int*)d_in[2];
    const float* m1w1 = (const float*)d_in[4];
    const float* m1b1 = (const float*)d_in[5];
    const float* m1w2 = (const float*)d_in[6];
    const float* m1b2 = (const float*)d_in[7];
    const float* m2w1 = (const float*)d_in[8];
    const float* m2b1 = (const float*)d_in[9];
    const float* m2w2 = (const float*)d_in[10];
    const float* m2b2 = (const float*)d_in[11];
    const float* fc1w = (const float*)d_in[12];
    const float* fc1b = (const float*)d_in[13];
    const float* bn1g = (const float*)d_in[14];
    const float* bn1b = (const float*)d_in[15];
    const float* fc2w = (const float*)d_in[16];
    const float* fc2b = (const float*)d_in[17];
    const float* bn2g = (const float*)d_in[18];
    const float* bn2b = (const float*)d_in[19];
    const float* resw = (const float*)d_in[20];
    float* out = (float*)d_out;

    char* ws = (char*)d_ws;
    // Zone A [0, 76.8MB): v1,v2 -> agg1 (bf16, 38.4MB) -> agg2 (bf16, 76.8MB)
    float*  v1   = (float*)(ws);
    float*  v2   = (float*)(ws + (size_t)NE * 4);
    __bf16* agg1 = (__bf16*)(ws);
    __bf16* agg2 = (__bf16*)(ws);
    const size_t offB = 76800000;   // h1raw fp32 (51.2MB) -> h2raw overlay
    float* h1raw = (float*)(ws + offB);
    float* h2raw = h1raw;
    const size_t offC = 128000000;  // hbn bf16 (25.6MB)
    __bf16* hbn = (__bf16*)(ws + offC);
    const size_t offD = 153600000;  // resb fp32 (51.2MB)
    float* resb = (float*)(ws + offD);
    const size_t offE = 204800000;  // xbf (12.8MB)
    __bf16* xbf = (__bf16*)(ws + offE);
    const size_t offF = 217600000;  // perm (12.8MB)
    float4* perm = (float4*)(ws + offF);
    const size_t offG = 230400000;  // small buffers
    int* row_start = (int*)(ws + offG);                 // 200064 B
    int* cursor    = (int*)(ws + offG + 200064);        // 200064 B (counts)
    int* blksum    = (int*)(ws + offG + 400128);
    int* blkoff    = (int*)(ws + offG + 401152);
    float* stats   = (float*)(ws + offG + 402176);      // 1024 floats
    __bf16* efrag  = (__bf16*)(ws + offG + 406272);     // 16 KB
    __bf16* bfrag1 = (__bf16*)(ws + offG + 422656);     // 384*256*2 = 196608
    __bf16* bfrag2 = (__bf16*)(ws + offG + 619264);     // 768*256*2 = 393216
    __bf16* bfragR = (__bf16*)(ws + offG + 1012480);    // 128*256*2 = 65536

    dim3 b256(256);

    // 0) conversions / weight packing
    cvt_bf16_kernel<<<3125, b256, 0, stream>>>(x, xbf, NN * FIN / 8);
    prep_w_kernel<<<32, b256, 0, stream>>>(m1w1, m2w1, efrag);
    prep_b_kernel<<<384, b256, 0, stream>>>(fc1w, bfrag1, 384);
    prep_b_kernel<<<768, b256, 0, stream>>>(fc2w, bfrag2, 768);
    prep_b_kernel<<<128, b256, 0, stream>>>(resw, bfragR, 128);

    // 1) edge MLP -> v1, v2
    edge_mlp_mfma<<<1024, b256, 0, stream>>>(xbf, widx, widx + NE, efrag,
        m1b1, m1w2, m1b2, m2b1, m2w2, m2b2, v1, v2);

    // 2) CSR build
    hipMemsetAsync(cursor, 0, NN * 4, stream);
    hist_kernel<<<NE / 256, b256, 0, stream>>>(widx, cursor);
    scan1_kernel<<<NCHUNK, b256, 0, stream>>>(cursor, blksum);
    scan2_kernel<<<1, b256, 0, stream>>>(blksum, blkoff);
    scan3_kernel<<<NCHUNK, b256, 0, stream>>>(cursor, blkoff, row_start);
    hipMemsetAsync(cursor, 0, NN * 4, stream);
    fill_kernel<<<NE / 256, b256, 0, stream>>>(widx, widx + NE, v1, v2, row_start, cursor, perm);

    // 3) conv1
    spmm1_kernel<<<NN / 4, b256, 0, stream>>>(xbf, wid, row_start, perm, agg1);
    hipMemsetAsync(stats, 0, 1024 * 4, stream);
    gemm_mfma<<<(NN + GBM - 1) / GBM, b256, 0, stream>>>(
        agg1, bfrag1, fc1b, h1raw, NN, 384, stats, stats + 256);
    bn_relu_kernel<<<NN * FOUT / 4 / 256, b256, 0, stream>>>(h1raw, stats, bn1g, bn1b, hbn);

    // 4) conv2 + residual
    spmm2_kernel<<<NN / 4, b256, 0, stream>>>(hbn, wid, row_start, perm, agg2);
    gemm_mfma<<<(NN + GBM - 1) / GBM, b256, 0, stream>>>(
        agg2, bfrag2, fc2b, h2raw, NN, 768, stats + 512, stats + 768);
    gemm_mfma<<<(NN + GBM - 1) / GBM, b256, 0, stream>>>(
        xbf, bfragR, nullptr, resb, NN, 128, nullptr, nullptr);
    final_kernel<<<NN * FOUT / 4 / 256, b256, 0, stream>>>(h2raw, stats + 512, bn2g, bn2b, resb, out);
}

// Round 4
// 558.178 us; speedup vs baseline: 2.7427x; 1.5040x over previous
//
#include <hip/hip_runtime.h>
#include <hip/hip_bf16.h>
#include <math.h>

#define NN 50000
#define NE 800000
#define FIN 128
#define FOUT 256
#define EPSF 1e-5f
#define NCHUNK 196  // ceil(NN/256)

typedef __bf16 bf16x8 __attribute__((ext_vector_type(8)));
typedef __bf16 bf16x4 __attribute__((ext_vector_type(4)));
typedef __bf16 bf16x2 __attribute__((ext_vector_type(2)));
typedef float f32x4 __attribute__((ext_vector_type(4)));

// ---------------------------------------------------------------------------
// fp32 -> bf16 convert (8 elems/thread)
// ---------------------------------------------------------------------------
__global__ void cvt_bf16_kernel(const float* __restrict__ in, __bf16* __restrict__ out, int n8) {
    int idx = blockIdx.x * 256 + threadIdx.x;
    if (idx >= n8) return;
    float4 a = ((const float4*)in)[idx * 2 + 0];
    float4 b = ((const float4*)in)[idx * 2 + 1];
    bf16x8 v = {(__bf16)a.x, (__bf16)a.y, (__bf16)a.z, (__bf16)a.w,
                (__bf16)b.x, (__bf16)b.y, (__bf16)b.z, (__bf16)b.w};
    ((bf16x8*)out)[idx] = v;
}

// ---------------------------------------------------------------------------
// Pack dense B [K x 256] fp32 row-major into MFMA B-fragment order bf16:
// frag[((kk*16+ct)*64+l)*8+i] = B[kk*32+(l>>4)*8+i][ct*16+(l&15)]
// ---------------------------------------------------------------------------
__global__ void prep_b_kernel(const float* __restrict__ B, __bf16* __restrict__ frag, int K) {
    int idx = blockIdx.x * 256 + threadIdx.x;
    if (idx >= K * 256) return;
    int i = idx & 7, l = (idx >> 3) & 63, ct = (idx >> 9) & 15, kk = idx >> 13;
    int k = kk * 32 + (l >> 4) * 8 + i;
    int c = ct * 16 + (l & 15);
    frag[idx] = (__bf16)B[k * 256 + c];
}

// ---------------------------------------------------------------------------
// Pack combined edge-MLP weights W1 [128k x 64c] (cols 0..31=mlp1, 32..63=mlp2)
// ---------------------------------------------------------------------------
__global__ void prep_w_kernel(const float* __restrict__ w1a, const float* __restrict__ w1b,
                              __bf16* __restrict__ fragbuf)
{
    int idx = blockIdx.x * 256 + threadIdx.x;  // 8192 total
    if (idx >= 8192) return;
    int i = idx & 7, l = (idx >> 3) & 63, ct = (idx >> 9) & 3, kt = idx >> 11;
    int n = l & 15, kb = l >> 4;
    int k = kt * 32 + kb * 8 + i;
    int c = ct * 16 + n;
    float w = (c < 32) ? w1a[k * 32 + c] : w1b[k * 32 + (c - 32)];
    fragbuf[idx] = (__bf16)w;
}

// ---------------------------------------------------------------------------
// Edge MLP via MFMA, zero LDS, no barriers; x gathered as bf16 (16B/lane/kt).
// ---------------------------------------------------------------------------
__global__ __launch_bounds__(256) void edge_mlp_mfma(
    const __bf16* __restrict__ x, const int* __restrict__ rowi, const int* __restrict__ coli,
    const __bf16* __restrict__ fragbuf,
    const float* __restrict__ b1a, const float* __restrict__ w2a, const float* __restrict__ b2a,
    const float* __restrict__ b1b, const float* __restrict__ w2b, const float* __restrict__ b2b,
    float* __restrict__ v1out, float* __restrict__ v2out)
{
    int lane = threadIdx.x & 63;
    int gwave = (blockIdx.x * 256 + threadIdx.x) >> 6;
    int nwaves = (gridDim.x * 256) >> 6;

    bf16x8 bfrag[4][4];
    const bf16x8* fb = (const bf16x8*)fragbuf;
#pragma unroll
    for (int kt = 0; kt < 4; kt++)
#pragma unroll
        for (int ct = 0; ct < 4; ct++)
            bfrag[kt][ct] = fb[(kt * 4 + ct) * 64 + lane];

    int n = lane & 15;
    int kb = lane >> 4;
    float b1c[4], w2c[4];
#pragma unroll
    for (int ct = 0; ct < 4; ct++) {
        int c = ct * 16 + n;
        b1c[ct] = (c < 32) ? b1a[c] : b1b[c - 32];
        w2c[ct] = (c < 32) ? w2a[c] : w2b[c - 32];
    }
    float bias2a = b2a[0], bias2b = b2b[0];

    const int ngroups = NE / 16;
    for (int g = gwave; g < ngroups; g += nwaves) {
        int e = g * 16 + n;
        int er = rowi[e], ec = coli[e];
        const __bf16* xr = x + (size_t)er * FIN + kb * 8;
        const __bf16* xc = x + (size_t)ec * FIN + kb * 8;
        f32x4 acc[4] = {{0.f, 0.f, 0.f, 0.f}, {0.f, 0.f, 0.f, 0.f},
                        {0.f, 0.f, 0.f, 0.f}, {0.f, 0.f, 0.f, 0.f}};
#pragma unroll
        for (int kt = 0; kt < 4; kt++) {
            bf16x8 a = *(const bf16x8*)(xr + kt * 32);
            bf16x8 c = *(const bf16x8*)(xc + kt * 32);
            bf16x8 af;
#pragma unroll
            for (int i = 0; i < 8; i++)
                af[i] = (__bf16)fabsf((float)a[i] - (float)c[i]);
#pragma unroll
            for (int ct = 0; ct < 4; ct++)
                acc[ct] = __builtin_amdgcn_mfma_f32_16x16x32_bf16(af, bfrag[kt][ct], acc[ct], 0, 0, 0);
        }
        float p1[4], p2[4];
#pragma unroll
        for (int r = 0; r < 4; r++) {
            float h0 = fmaxf(acc[0][r] + b1c[0], 0.f) * w2c[0];
            float h1 = fmaxf(acc[1][r] + b1c[1], 0.f) * w2c[1];
            float h2 = fmaxf(acc[2][r] + b1c[2], 0.f) * w2c[2];
            float h3 = fmaxf(acc[3][r] + b1c[3], 0.f) * w2c[3];
            p1[r] = h0 + h1;
            p2[r] = h2 + h3;
        }
#pragma unroll
        for (int off = 1; off < 16; off <<= 1)
#pragma unroll
            for (int r = 0; r < 4; r++) {
                p1[r] += __shfl_xor(p1[r], off, 64);
                p2[r] += __shfl_xor(p2[r], off, 64);
            }
        if (n == 0) {
#pragma unroll
            for (int r = 0; r < 4; r++) {
                int eo = g * 16 + kb * 4 + r;
                v1out[eo] = 1.f / (1.f + expf(-(p1[r] + bias2a)));
                v2out[eo] = 1.f / (1.f + expf(-(p2[r] + bias2b)));
            }
        }
    }
}

// ---------------------------------------------------------------------------
// CSR build: histogram, 3-kernel exclusive scan, fill (packed col/v1/v2).
// ---------------------------------------------------------------------------
__global__ void hist_kernel(const int* __restrict__ rowi, int* __restrict__ counts) {
    int e = blockIdx.x * 256 + threadIdx.x;
    if (e < NE) atomicAdd(&counts[rowi[e]], 1);
}

__global__ void scan1_kernel(const int* __restrict__ counts, int* __restrict__ blksum) {
    __shared__ int s[256];
    int t = threadIdx.x, idx = blockIdx.x * 256 + t;
    s[t] = (idx < NN) ? counts[idx] : 0;
    __syncthreads();
    for (int off = 128; off > 0; off >>= 1) {
        if (t < off) s[t] += s[t + off];
        __syncthreads();
    }
    if (t == 0) blksum[blockIdx.x] = s[0];
}

__global__ void scan2_kernel(const int* __restrict__ blksum, int* __restrict__ blkoff) {
    __shared__ int s[256];
    int t = threadIdx.x;
    int v = (t < NCHUNK) ? blksum[t] : 0;
    s[t] = v; __syncthreads();
    for (int off = 1; off < 256; off <<= 1) {
        int xv = (t >= off) ? s[t - off] : 0;
        __syncthreads();
        s[t] += xv;
        __syncthreads();
    }
    if (t < NCHUNK) blkoff[t] = s[t] - v;  // exclusive
}

__global__ void scan3_kernel(const int* __restrict__ counts, const int* __restrict__ blkoff,
                             int* __restrict__ row_start) {
    __shared__ int s[256];
    int t = threadIdx.x, idx = blockIdx.x * 256 + t;
    int v = (idx < NN) ? counts[idx] : 0;
    s[t] = v; __syncthreads();
    for (int off = 1; off < 256; off <<= 1) {
        int xv = (t >= off) ? s[t - off] : 0;
        __syncthreads();
        s[t] += xv;
        __syncthreads();
    }
    if (idx <= NN) row_start[idx] = s[t] - v + blkoff[blockIdx.x];
}

__global__ void fill_kernel(const int* __restrict__ rowi, const int* __restrict__ coli,
                            const float* __restrict__ v1, const float* __restrict__ v2,
                            const int* __restrict__ row_start, int* __restrict__ cursor,
                            float4* __restrict__ perm) {
    int e = blockIdx.x * 256 + threadIdx.x;
    if (e >= NE) return;
    int r = rowi[e];
    int p = row_start[r] + atomicAdd(&cursor[r], 1);
    float4 qv;
    qv.x = __int_as_float(coli[e]);
    qv.y = v1[e];
    qv.z = v2[e];
    qv.w = 0.f;
    perm[p] = qv;
}

// ---------------------------------------------------------------------------
// spmm: one wave per node, bf16 gathers, fp32 accumulate, bf16 agg out.
// ---------------------------------------------------------------------------
__global__ __launch_bounds__(256) void spmm1_kernel(
    const __bf16* __restrict__ x, const float* __restrict__ wid,
    const int* __restrict__ row_start, const float4* __restrict__ perm,
    __bf16* __restrict__ agg)
{
    int lane = threadIdx.x & 63;
    int i = blockIdx.x * 4 + (threadIdx.x >> 6);
    if (i >= NN) return;
    int f0 = lane * 2;
    float a1x = 0, a1y = 0, a2x = 0, a2y = 0;
    int p0 = row_start[i], p1 = row_start[i + 1];
    for (int p = p0; p < p1; p++) {
        float4 pr = perm[p];
        int c = __float_as_int(pr.x);
        bf16x2 f = *(const bf16x2*)(x + (size_t)c * FIN + f0);
        float fx = (float)f[0], fy = (float)f[1];
        a1x += pr.y * fx; a1y += pr.y * fy;
        a2x += pr.z * fx; a2y += pr.z * fy;
    }
    float w = wid[i];
    bf16x2 xi = *(const bf16x2*)(x + (size_t)i * FIN + f0);
    __bf16* ag = agg + (size_t)i * 384;
    *(bf16x2*)(ag + f0) = (bf16x2){(__bf16)(w * (float)xi[0]), (__bf16)(w * (float)xi[1])};
    *(bf16x2*)(ag + FIN + f0) = (bf16x2){(__bf16)a1x, (__bf16)a1y};
    *(bf16x2*)(ag + 2 * FIN + f0) = (bf16x2){(__bf16)a2x, (__bf16)a2y};
}

__global__ __launch_bounds__(256) void spmm2_kernel(
    const __bf16* __restrict__ h, const float* __restrict__ wid,
    const int* __restrict__ row_start, const float4* __restrict__ perm,
    __bf16* __restrict__ agg)
{
    int lane = threadIdx.x & 63;
    int i = blockIdx.x * 4 + (threadIdx.x >> 6);
    if (i >= NN) return;
    int f0 = lane * 4;
    float s1x = 0, s1y = 0, s1z = 0, s1w = 0, s2x = 0, s2y = 0, s2z = 0, s2w = 0;
    int p0 = row_start[i], p1 = row_start[i + 1];
    for (int p = p0; p < p1; p++) {
        float4 pr = perm[p];
        int c = __float_as_int(pr.x);
        bf16x4 f = *(const bf16x4*)(h + (size_t)c * FOUT + f0);
        float fx = (float)f[0], fy = (float)f[1], fz = (float)f[2], fw = (float)f[3];
        s1x += pr.y * fx; s1y += pr.y * fy; s1z += pr.y * fz; s1w += pr.y * fw;
        s2x += pr.z * fx; s2y += pr.z * fy; s2z += pr.z * fz; s2w += pr.z * fw;
    }
    float w = wid[i];
    bf16x4 hi = *(const bf16x4*)(h + (size_t)i * FOUT + f0);
    __bf16* ag = agg + (size_t)i * 768;
    *(bf16x4*)(ag + f0) = (bf16x4){(__bf16)(w * (float)hi[0]), (__bf16)(w * (float)hi[1]),
                                   (__bf16)(w * (float)hi[2]), (__bf16)(w * (float)hi[3])};
    *(bf16x4*)(ag + FOUT + f0) = (bf16x4){(__bf16)s1x, (__bf16)s1y, (__bf16)s1z, (__bf16)s1w};
    *(bf16x4*)(ag + 2 * FOUT + f0) = (bf16x4){(__bf16)s2x, (__bf16)s2y, (__bf16)s2z, (__bf16)s2w};
}

// ---------------------------------------------------------------------------
// bf16 MFMA GEMM, LDS-staged B: C[M,256] = A[M,K]@B[K,256] (+bias)(+BN stats).
// Grid (ceil(M/128), 2). Block: 4 waves; wave w = rows [blk*128+w*32, +32),
// cols [bn*128, +128). Per 64-K chunk: B (16KB, frag-order) reg-staged to LDS,
// then 2 k-steps: 2 A-frag global loads + 8 conflict-free ds_reads + 16 MFMA.
// C stored bf16.
// ---------------------------------------------------------------------------
#define GBM 128
__global__ __launch_bounds__(256) void gemm_mfma(
    const __bf16* __restrict__ A, const __bf16* __restrict__ Bfrag,
    const float* __restrict__ bias, __bf16* __restrict__ C,
    int M, int K, float* __restrict__ colsum, float* __restrict__ colsq)
{
    __shared__ __bf16 bs[8192];     // 16KB chunk
    __shared__ float lsum[128], lsq[128];
    int t = threadIdx.x, lane = t & 63, w = t >> 6;
    int bn = blockIdx.y;
    int n = lane & 15, kb = lane >> 4;
    int rowbase = blockIdx.x * GBM + w * 32;
    int r0 = rowbase + n;      if (r0 > M - 1) r0 = M - 1;
    int r1 = rowbase + 16 + n; if (r1 > M - 1) r1 = M - 1;
    const __bf16* ap0 = A + (size_t)r0 * K + kb * 8;
    const __bf16* ap1 = A + (size_t)r1 * K + kb * 8;

    f32x4 acc[2][8];
#pragma unroll
    for (int rf = 0; rf < 2; rf++)
#pragma unroll
        for (int ct = 0; ct < 8; ct++) acc[rf][ct] = (f32x4){0.f, 0.f, 0.f, 0.f};

    int nc = K >> 6;
    for (int kc = 0; kc < nc; kc++) {
        bf16x8 stg[4];
#pragma unroll
        for (int it = 0; it < 4; it++) {
            int o = it * 2048 + t * 8;
            int p = o >> 12, j = (o >> 9) & 7, rem = o & 511;
            int ge = ((kc * 2 + p) * 16 + 8 * bn + j) * 512 + rem;
            stg[it] = *(const bf16x8*)(Bfrag + ge);
        }
        __syncthreads();  // prior chunk's compute done
#pragma unroll
        for (int it = 0; it < 4; it++)
            *(bf16x8*)&bs[it * 2048 + t * 8] = stg[it];
        __syncthreads();  // chunk staged
#pragma unroll
        for (int ks = 0; ks < 2; ks++) {
            int kk = kc * 64 + ks * 32;
            bf16x8 a0 = *(const bf16x8*)(ap0 + kk);
            bf16x8 a1 = *(const bf16x8*)(ap1 + kk);
#pragma unroll
            for (int ct = 0; ct < 8; ct++) {
                bf16x8 bf = *(const bf16x8*)&bs[ks * 4096 + ct * 512 + lane * 8];
                acc[0][ct] = __builtin_amdgcn_mfma_f32_16x16x32_bf16(a0, bf, acc[0][ct], 0, 0, 0);
                acc[1][ct] = __builtin_amdgcn_mfma_f32_16x16x32_bf16(a1, bf, acc[1][ct], 0, 0, 0);
            }
        }
    }

    bool dostats = (colsum != nullptr);
    if (dostats) {
        if (t < 128) { lsum[t] = 0.f; lsq[t] = 0.f; }
        __syncthreads();
    }
#pragma unroll
    for (int rf = 0; rf < 2; rf++) {
        int rbase = rowbase + rf * 16 + kb * 4;
#pragma unroll
        for (int ct = 0; ct < 8; ct++) {
            int col = bn * 128 + ct * 16 + n;
            float bv = bias ? bias[col] : 0.f;
            float ps = 0.f, pq = 0.f;
#pragma unroll
            for (int r = 0; r < 4; r++) {
                int gm = rbase + r;
                if (gm < M) {
                    float v = acc[rf][ct][r] + bv;
                    C[(size_t)gm * 256 + col] = (__bf16)v;
                    ps += v; pq += v * v;
                }
            }
            if (dostats) {
                ps += __shfl_xor(ps, 16, 64); pq += __shfl_xor(pq, 16, 64);
                ps += __shfl_xor(ps, 32, 64); pq += __shfl_xor(pq, 32, 64);
                if (lane < 16) {
                    atomicAdd(&lsum[ct * 16 + n], ps);
                    atomicAdd(&lsq[ct * 16 + n], pq);
                }
            }
        }
    }
    if (dostats) {
        __syncthreads();
        if (t < 128) {
            atomicAdd(&colsum[bn * 128 + t], lsum[t]);
            atomicAdd(&colsq[bn * 128 + t], lsq[t]);
        }
    }
}

// ---------------------------------------------------------------------------
// BN apply (+relu) bf16->bf16, and final BN+residual+relu bf16->fp32.
// stats layout: [0:256)=colsum, [256:512)=colsumsq
// ---------------------------------------------------------------------------
__device__ __forceinline__ float bn1c(float v, float s, float q, float g, float b) {
    const float invn = 1.0f / (float)NN;
    float mu = s * invn;
    float var = q * invn - mu * mu;
    float r = rsqrtf(var + EPSF);
    return (v - mu) * r * g + b;
}

__global__ __launch_bounds__(256) void bn_relu_kernel(
    const __bf16* __restrict__ h, const float* __restrict__ stats,
    const float* __restrict__ g, const float* __restrict__ b, __bf16* __restrict__ o)
{
    size_t idx = (size_t)blockIdx.x * 256 + threadIdx.x;
    int j = ((int)idx & 31) * 8;
    bf16x8 v = ((const bf16x8*)h)[idx];
    bf16x8 r;
#pragma unroll
    for (int u = 0; u < 8; u++)
        r[u] = (__bf16)fmaxf(bn1c((float)v[u], stats[j + u], stats[256 + j + u], g[j + u], b[j + u]), 0.f);
    ((bf16x8*)o)[idx] = r;
}

__global__ __launch_bounds__(256) void final_kernel(
    const __bf16* __restrict__ h2, const float* __restrict__ stats,
    const float* __restrict__ g, const float* __restrict__ b,
    const __bf16* __restrict__ resb, float* __restrict__ o)
{
    size_t idx = (size_t)blockIdx.x * 256 + threadIdx.x;
    int j = ((int)idx & 31) * 8;
    bf16x8 v = ((const bf16x8*)h2)[idx];
    bf16x8 rr = ((const bf16x8*)resb)[idx];
    float r[8];
#pragma unroll
    for (int u = 0; u < 8; u++)
        r[u] = fmaxf(bn1c((float)v[u], stats[j + u], stats[256 + j + u], g[j + u], b[j + u]) + (float)rr[u], 0.f);
    float4 o0 = {r[0], r[1], r[2], r[3]}, o1 = {r[4], r[5], r[6], r[7]};
    ((float4*)o)[idx * 2 + 0] = o0;
    ((float4*)o)[idx * 2 + 1] = o1;
}

// ---------------------------------------------------------------------------
extern "C" void kernel_launch(void* const* d_in, const int* in_sizes, int n_in,
                              void* d_out, int out_size, void* d_ws, size_t ws_size,
                              hipStream_t stream)
{
    (void)in_sizes; (void)n_in; (void)out_size; (void)ws_size;
    const float* x    = (const float*)d_in[0];
    const float* wid  = (const float*)d_in[1];
    const int*   widx = (const int*)d_in[2];
    const float* m1w1 = (const float*)d_in[4];
    const float* m1b1 = (const float*)d_in[5];
    const float* m1w2 = (const float*)d_in[6];
    const float* m1b2 = (const float*)d_in[7];
    const float* m2w1 = (const float*)d_in[8];
    const float* m2b1 = (const float*)d_in[9];
    const float* m2w2 = (const float*)d_in[10];
    const float* m2b2 = (const float*)d_in[11];
    const float* fc1w = (const float*)d_in[12];
    const float* fc1b = (const float*)d_in[13];
    const float* bn1g = (const float*)d_in[14];
    const float* bn1b = (const float*)d_in[15];
    const float* fc2w = (const float*)d_in[16];
    const float* fc2b = (const float*)d_in[17];
    const float* bn2g = (const float*)d_in[18];
    const float* bn2b = (const float*)d_in[19];
    const float* resw = (const float*)d_in[20];
    float* out = (float*)d_out;

    char* ws = (char*)d_ws;
    // Zone A [0, 76.8MB): v1,v2 -> agg1 (bf16, 38.4MB) -> agg2 (bf16, 76.8MB)
    float*  v1   = (float*)(ws);
    float*  v2   = (float*)(ws + (size_t)NE * 4);
    __bf16* agg1 = (__bf16*)(ws);
    __bf16* agg2 = (__bf16*)(ws);
    const size_t offB = 76800000;   // h1 bf16 (25.6MB) -> h2 overlay
    __bf16* h1 = (__bf16*)(ws + offB);
    __bf16* h2 = h1;
    const size_t offC = 128000000;  // hbn bf16 (25.6MB)
    __bf16* hbn = (__bf16*)(ws + offC);
    const size_t offD = 153600000;  // resb bf16 (25.6MB)
    __bf16* resb = (__bf16*)(ws + offD);
    const size_t offE = 204800000;  // xbf (12.8MB)
    __bf16* xbf = (__bf16*)(ws + offE);
    const size_t offF = 217600000;  // perm (12.8MB)
    float4* perm = (float4*)(ws + offF);
    const size_t offG = 230400000;  // small buffers
    int* row_start = (int*)(ws + offG);                 // 200064 B
    int* cursor    = (int*)(ws + offG + 200064);        // 200064 B (counts)
    int* blksum    = (int*)(ws + offG + 400128);
    int* blkoff    = (int*)(ws + offG + 401152);
    float* stats   = (float*)(ws + offG + 402176);      // 1024 floats
    __bf16* efrag  = (__bf16*)(ws + offG + 406272);     // 16 KB
    __bf16* bfrag1 = (__bf16*)(ws + offG + 422656);     // 384*256*2 = 196608
    __bf16* bfrag2 = (__bf16*)(ws + offG + 619264);     // 768*256*2 = 393216
    __bf16* bfragR = (__bf16*)(ws + offG + 1012480);    // 128*256*2 = 65536

    dim3 b256(256);
    dim3 ggrid((NN + GBM - 1) / GBM, 2);

    // 0) conversions / weight packing
    cvt_bf16_kernel<<<3125, b256, 0, stream>>>(x, xbf, NN * FIN / 8);
    prep_w_kernel<<<32, b256, 0, stream>>>(m1w1, m2w1, efrag);
    prep_b_kernel<<<384, b256, 0, stream>>>(fc1w, bfrag1, 384);
    prep_b_kernel<<<768, b256, 0, stream>>>(fc2w, bfrag2, 768);
    prep_b_kernel<<<128, b256, 0, stream>>>(resw, bfragR, 128);

    // 1) edge MLP -> v1, v2
    edge_mlp_mfma<<<1024, b256, 0, stream>>>(xbf, widx, widx + NE, efrag,
        m1b1, m1w2, m1b2, m2b1, m2w2, m2b2, v1, v2);

    // 2) CSR build
    hipMemsetAsync(cursor, 0, NN * 4, stream);
    hist_kernel<<<NE / 256, b256, 0, stream>>>(widx, cursor);
    scan1_kernel<<<NCHUNK, b256, 0, stream>>>(cursor, blksum);
    scan2_kernel<<<1, b256, 0, stream>>>(blksum, blkoff);
    scan3_kernel<<<NCHUNK, b256, 0, stream>>>(cursor, blkoff, row_start);
    hipMemsetAsync(cursor, 0, NN * 4, stream);
    fill_kernel<<<NE / 256, b256, 0, stream>>>(widx, widx + NE, v1, v2, row_start, cursor, perm);

    // 3) conv1
    spmm1_kernel<<<NN / 4, b256, 0, stream>>>(xbf, wid, row_start, perm, agg1);
    hipMemsetAsync(stats, 0, 1024 * 4, stream);
    gemm_mfma<<<ggrid, b256, 0, stream>>>(agg1, bfrag1, fc1b, h1, NN, 384, stats, stats + 256);
    bn_relu_kernel<<<NN * FOUT / 8 / 256, b256, 0, stream>>>(h1, stats, bn1g, bn1b, hbn);

    // 4) conv2 + residual
    spmm2_kernel<<<NN / 4, b256, 0, stream>>>(hbn, wid, row_start, perm, agg2);
    gemm_mfma<<<ggrid, b256, 0, stream>>>(agg2, bfrag2, fc2b, h2, NN, 768, stats + 512, stats + 768);
    gemm_mfma<<<ggrid, b256, 0, stream>>>(xbf, bfragR, nullptr, resb, NN, 128, nullptr, nullptr);
    final_kernel<<<NN * FOUT / 8 / 256, b256, 0, stream>>>(h2, stats + 512, bn2g, bn2b, resb, out);
}

// Round 5
// 538.483 us; speedup vs baseline: 2.8431x; 1.0366x over previous
//
#include <hip/hip_runtime.h>
#include <hip/hip_bf16.h>
#include <math.h>

#define NN 50000
#define NE 800000
#define FIN 128
#define FOUT 256
#define EPSF 1e-5f
#define NCHUNK 196  // ceil(NN/256)

typedef __bf16 bf16x8 __attribute__((ext_vector_type(8)));
typedef __bf16 bf16x4 __attribute__((ext_vector_type(4)));
typedef __bf16 bf16x2 __attribute__((ext_vector_type(2)));
typedef float f32x4 __attribute__((ext_vector_type(4)));

// ---------------------------------------------------------------------------
// fp32 -> bf16 convert (8 elems/thread)
// ---------------------------------------------------------------------------
__global__ void cvt_bf16_kernel(const float* __restrict__ in, __bf16* __restrict__ out, int n8) {
    int idx = blockIdx.x * 256 + threadIdx.x;
    if (idx >= n8) return;
    float4 a = ((const float4*)in)[idx * 2 + 0];
    float4 b = ((const float4*)in)[idx * 2 + 1];
    bf16x8 v = {(__bf16)a.x, (__bf16)a.y, (__bf16)a.z, (__bf16)a.w,
                (__bf16)b.x, (__bf16)b.y, (__bf16)b.z, (__bf16)b.w};
    ((bf16x8*)out)[idx] = v;
}

// ---------------------------------------------------------------------------
// Pack dense B [K x 256] fp32 row-major into MFMA B-fragment order bf16:
// frag[((kk*16+ct)*64+l)*8+i] = B[kk*32+(l>>4)*8+i][ct*16+(l&15)]
// ---------------------------------------------------------------------------
__global__ void prep_b_kernel(const float* __restrict__ B, __bf16* __restrict__ frag, int K) {
    int idx = blockIdx.x * 256 + threadIdx.x;
    if (idx >= K * 256) return;
    int i = idx & 7, l = (idx >> 3) & 63, ct = (idx >> 9) & 15, kk = idx >> 13;
    int k = kk * 32 + (l >> 4) * 8 + i;
    int c = ct * 16 + (l & 15);
    frag[idx] = (__bf16)B[k * 256 + c];
}

// ---------------------------------------------------------------------------
// Pack combined edge-MLP weights W1 [128k x 64c] (cols 0..31=mlp1, 32..63=mlp2)
// ---------------------------------------------------------------------------
__global__ void prep_w_kernel(const float* __restrict__ w1a, const float* __restrict__ w1b,
                              __bf16* __restrict__ fragbuf)
{
    int idx = blockIdx.x * 256 + threadIdx.x;  // 8192 total
    if (idx >= 8192) return;
    int i = idx & 7, l = (idx >> 3) & 63, ct = (idx >> 9) & 3, kt = idx >> 11;
    int n = l & 15, kb = l >> 4;
    int k = kt * 32 + kb * 8 + i;
    int c = ct * 16 + n;
    float w = (c < 32) ? w1a[k * 32 + c] : w1b[k * 32 + (c - 32)];
    fragbuf[idx] = (__bf16)w;
}

// ---------------------------------------------------------------------------
// CSR build: histogram, 3-kernel exclusive scan, fill (col,row) int2.
// ---------------------------------------------------------------------------
__global__ void hist_kernel(const int* __restrict__ rowi, int* __restrict__ counts) {
    int e = blockIdx.x * 256 + threadIdx.x;
    if (e < NE) atomicAdd(&counts[rowi[e]], 1);
}

__global__ void scan1_kernel(const int* __restrict__ counts, int* __restrict__ blksum) {
    __shared__ int s[256];
    int t = threadIdx.x, idx = blockIdx.x * 256 + t;
    s[t] = (idx < NN) ? counts[idx] : 0;
    __syncthreads();
    for (int off = 128; off > 0; off >>= 1) {
        if (t < off) s[t] += s[t + off];
        __syncthreads();
    }
    if (t == 0) blksum[blockIdx.x] = s[0];
}

__global__ void scan2_kernel(const int* __restrict__ blksum, int* __restrict__ blkoff) {
    __shared__ int s[256];
    int t = threadIdx.x;
    int v = (t < NCHUNK) ? blksum[t] : 0;
    s[t] = v; __syncthreads();
    for (int off = 1; off < 256; off <<= 1) {
        int xv = (t >= off) ? s[t - off] : 0;
        __syncthreads();
        s[t] += xv;
        __syncthreads();
    }
    if (t < NCHUNK) blkoff[t] = s[t] - v;  // exclusive
}

__global__ void scan3_kernel(const int* __restrict__ counts, const int* __restrict__ blkoff,
                             int* __restrict__ row_start) {
    __shared__ int s[256];
    int t = threadIdx.x, idx = blockIdx.x * 256 + t;
    int v = (idx < NN) ? counts[idx] : 0;
    s[t] = v; __syncthreads();
    for (int off = 1; off < 256; off <<= 1) {
        int xv = (t >= off) ? s[t - off] : 0;
        __syncthreads();
        s[t] += xv;
        __syncthreads();
    }
    if (idx <= NN) row_start[idx] = s[t] - v + blkoff[blockIdx.x];
}

__global__ void fill_kernel(const int* __restrict__ rowi, const int* __restrict__ coli,
                            const int* __restrict__ row_start, int* __restrict__ cursor,
                            int2* __restrict__ perm) {
    int e = blockIdx.x * 256 + threadIdx.x;
    if (e >= NE) return;
    int r = rowi[e];
    int p = row_start[r] + atomicAdd(&cursor[r], 1);
    perm[p] = make_int2(coli[e], r);
}

// ---------------------------------------------------------------------------
// Edge MLP via MFMA over CSR-ordered edges (row gathers ~cache-hits).
// 16 edges per wave-iter; writes v12[p] = (v1,v2) at CSR position.
// ---------------------------------------------------------------------------
__global__ __launch_bounds__(256) void edge_mlp_mfma(
    const __bf16* __restrict__ x, const int2* __restrict__ perm,
    const __bf16* __restrict__ fragbuf,
    const float* __restrict__ b1a, const float* __restrict__ w2a, const float* __restrict__ b2a,
    const float* __restrict__ b1b, const float* __restrict__ w2b, const float* __restrict__ b2b,
    float2* __restrict__ v12)
{
    int lane = threadIdx.x & 63;
    int gwave = (blockIdx.x * 256 + threadIdx.x) >> 6;
    int nwaves = (gridDim.x * 256) >> 6;

    bf16x8 bfrag[4][4];
    const bf16x8* fb = (const bf16x8*)fragbuf;
#pragma unroll
    for (int kt = 0; kt < 4; kt++)
#pragma unroll
        for (int ct = 0; ct < 4; ct++)
            bfrag[kt][ct] = fb[(kt * 4 + ct) * 64 + lane];

    int n = lane & 15;
    int kb = lane >> 4;
    float b1c[4], w2c[4];
#pragma unroll
    for (int ct = 0; ct < 4; ct++) {
        int c = ct * 16 + n;
        b1c[ct] = (c < 32) ? b1a[c] : b1b[c - 32];
        w2c[ct] = (c < 32) ? w2a[c] : w2b[c - 32];
    }
    float bias2a = b2a[0], bias2b = b2b[0];

    const int ngroups = NE / 16;
    for (int g = gwave; g < ngroups; g += nwaves) {
        int2 pe = perm[g * 16 + n];
        const __bf16* xr = x + (size_t)pe.y * FIN + kb * 8;
        const __bf16* xc = x + (size_t)pe.x * FIN + kb * 8;
        f32x4 acc[4] = {{0.f, 0.f, 0.f, 0.f}, {0.f, 0.f, 0.f, 0.f},
                        {0.f, 0.f, 0.f, 0.f}, {0.f, 0.f, 0.f, 0.f}};
#pragma unroll
        for (int kt = 0; kt < 4; kt++) {
            bf16x8 a = *(const bf16x8*)(xr + kt * 32);
            bf16x8 c = *(const bf16x8*)(xc + kt * 32);
            bf16x8 af;
#pragma unroll
            for (int i = 0; i < 8; i++)
                af[i] = (__bf16)fabsf((float)a[i] - (float)c[i]);
#pragma unroll
            for (int ct = 0; ct < 4; ct++)
                acc[ct] = __builtin_amdgcn_mfma_f32_16x16x32_bf16(af, bfrag[kt][ct], acc[ct], 0, 0, 0);
        }
        float p1[4], p2[4];
#pragma unroll
        for (int r = 0; r < 4; r++) {
            float h0 = fmaxf(acc[0][r] + b1c[0], 0.f) * w2c[0];
            float h1 = fmaxf(acc[1][r] + b1c[1], 0.f) * w2c[1];
            float h2 = fmaxf(acc[2][r] + b1c[2], 0.f) * w2c[2];
            float h3 = fmaxf(acc[3][r] + b1c[3], 0.f) * w2c[3];
            p1[r] = h0 + h1;
            p2[r] = h2 + h3;
        }
#pragma unroll
        for (int off = 1; off < 16; off <<= 1)
#pragma unroll
            for (int r = 0; r < 4; r++) {
                p1[r] += __shfl_xor(p1[r], off, 64);
                p2[r] += __shfl_xor(p2[r], off, 64);
            }
        if (n == 0) {
#pragma unroll
            for (int r = 0; r < 4; r++) {
                int p = g * 16 + kb * 4 + r;
                v12[p] = make_float2(1.f / (1.f + expf(-(p1[r] + bias2a))),
                                     1.f / (1.f + expf(-(p2[r] + bias2b))));
            }
        }
    }
}

// ---------------------------------------------------------------------------
// spmm: one wave per node; writes only [S1·feats | S2·feats] (no identity).
// ---------------------------------------------------------------------------
__global__ __launch_bounds__(256) void spmm1_kernel(
    const __bf16* __restrict__ x, const int2* __restrict__ perm,
    const float2* __restrict__ v12, const int* __restrict__ row_start,
    __bf16* __restrict__ agg)
{
    int lane = threadIdx.x & 63;
    int i = blockIdx.x * 4 + (threadIdx.x >> 6);
    if (i >= NN) return;
    int f0 = lane * 2;
    float a1x = 0, a1y = 0, a2x = 0, a2y = 0;
    int p0 = row_start[i], p1 = row_start[i + 1];
    for (int p = p0; p < p1; p++) {
        int c = perm[p].x;
        float2 vv = v12[p];
        bf16x2 f = *(const bf16x2*)(x + (size_t)c * FIN + f0);
        float fx = (float)f[0], fy = (float)f[1];
        a1x += vv.x * fx; a1y += vv.x * fy;
        a2x += vv.y * fx; a2y += vv.y * fy;
    }
    __bf16* ag = agg + (size_t)i * 256;
    *(bf16x2*)(ag + f0) = (bf16x2){(__bf16)a1x, (__bf16)a1y};
    *(bf16x2*)(ag + FIN + f0) = (bf16x2){(__bf16)a2x, (__bf16)a2y};
}

__global__ __launch_bounds__(256) void spmm2_kernel(
    const __bf16* __restrict__ h, const int2* __restrict__ perm,
    const float2* __restrict__ v12, const int* __restrict__ row_start,
    __bf16* __restrict__ agg)
{
    int lane = threadIdx.x & 63;
    int i = blockIdx.x * 4 + (threadIdx.x >> 6);
    if (i >= NN) return;
    int f0 = lane * 4;
    float s1x = 0, s1y = 0, s1z = 0, s1w = 0, s2x = 0, s2y = 0, s2z = 0, s2w = 0;
    int p0 = row_start[i], p1 = row_start[i + 1];
    for (int p = p0; p < p1; p++) {
        int c = perm[p].x;
        float2 vv = v12[p];
        bf16x4 f = *(const bf16x4*)(h + (size_t)c * FOUT + f0);
        float fx = (float)f[0], fy = (float)f[1], fz = (float)f[2], fw = (float)f[3];
        s1x += vv.x * fx; s1y += vv.x * fy; s1z += vv.x * fz; s1w += vv.x * fw;
        s2x += vv.y * fx; s2y += vv.y * fy; s2z += vv.y * fz; s2w += vv.y * fw;
    }
    __bf16* ag = agg + (size_t)i * 512;
    *(bf16x4*)(ag + f0) = (bf16x4){(__bf16)s1x, (__bf16)s1y, (__bf16)s1z, (__bf16)s1w};
    *(bf16x4*)(ag + FOUT + f0) = (bf16x4){(__bf16)s2x, (__bf16)s2y, (__bf16)s2z, (__bf16)s2w};
}

// ---------------------------------------------------------------------------
// Two-piece bf16 MFMA GEMM, LDS-staged B:
//   C = [wid ⊙] (A2[M,K2] @ B2) [+ A1[M,K1] @ B1] (+bias) (+BN col stats)
// Grid (ceil(M/128), 2); 4 waves; wave = 32 rows x 128 cols; C bf16.
// ---------------------------------------------------------------------------
#define GBM 128
__global__ __launch_bounds__(256) void gemm_mfma(
    const __bf16* __restrict__ A2, const __bf16* __restrict__ B2frag, int K2,
    const float* __restrict__ wid,
    const __bf16* __restrict__ A1, const __bf16* __restrict__ B1frag, int K1,
    const float* __restrict__ bias, __bf16* __restrict__ C, int M,
    float* __restrict__ colsum, float* __restrict__ colsq)
{
    __shared__ __bf16 bs[8192];     // 16KB chunk
    __shared__ float lsum[128], lsq[128];
    int t = threadIdx.x, lane = t & 63, w = t >> 6;
    int bn = blockIdx.y;
    int n = lane & 15, kb = lane >> 4;
    int rowbase = blockIdx.x * GBM + w * 32;
    int r0 = rowbase + n;      if (r0 > M - 1) r0 = M - 1;
    int r1 = rowbase + 16 + n; if (r1 > M - 1) r1 = M - 1;

    f32x4 acc[2][8];
#pragma unroll
    for (int rf = 0; rf < 2; rf++)
#pragma unroll
        for (int ct = 0; ct < 8; ct++) acc[rf][ct] = (f32x4){0.f, 0.f, 0.f, 0.f};

    // ---- phase A2 @ B2 ----
    {
        const __bf16* ap0 = A2 + (size_t)r0 * K2 + kb * 8;
        const __bf16* ap1 = A2 + (size_t)r1 * K2 + kb * 8;
        int nc = K2 >> 6;
        for (int kc = 0; kc < nc; kc++) {
            bf16x8 stg[4];
#pragma unroll
            for (int it = 0; it < 4; it++) {
                int o = it * 2048 + t * 8;
                int p = o >> 12, j = (o >> 9) & 7, rem = o & 511;
                int ge = ((kc * 2 + p) * 16 + 8 * bn + j) * 512 + rem;
                stg[it] = *(const bf16x8*)(B2frag + ge);
            }
            __syncthreads();
#pragma unroll
            for (int it = 0; it < 4; it++)
                *(bf16x8*)&bs[it * 2048 + t * 8] = stg[it];
            __syncthreads();
#pragma unroll
            for (int ks = 0; ks < 2; ks++) {
                int kk = kc * 64 + ks * 32;
                bf16x8 a0 = *(const bf16x8*)(ap0 + kk);
                bf16x8 a1 = *(const bf16x8*)(ap1 + kk);
#pragma unroll
                for (int ct = 0; ct < 8; ct++) {
                    bf16x8 bf = *(const bf16x8*)&bs[ks * 4096 + ct * 512 + lane * 8];
                    acc[0][ct] = __builtin_amdgcn_mfma_f32_16x16x32_bf16(a0, bf, acc[0][ct], 0, 0, 0);
                    acc[1][ct] = __builtin_amdgcn_mfma_f32_16x16x32_bf16(a1, bf, acc[1][ct], 0, 0, 0);
                }
            }
        }
    }

    // ---- per-row wid scale of the A2 partial ----
    if (wid) {
#pragma unroll
        for (int rf = 0; rf < 2; rf++) {
            int rb = rowbase + rf * 16 + kb * 4;
            float w4[4];
#pragma unroll
            for (int r = 0; r < 4; r++) {
                int gm = rb + r; if (gm > M - 1) gm = M - 1;
                w4[r] = wid[gm];
            }
#pragma unroll
            for (int ct = 0; ct < 8; ct++)
#pragma unroll
                for (int r = 0; r < 4; r++) acc[rf][ct][r] *= w4[r];
        }
    }

    // ---- phase A1 @ B1 ----
    if (A1) {
        const __bf16* ap0 = A1 + (size_t)r0 * K1 + kb * 8;
        const __bf16* ap1 = A1 + (size_t)r1 * K1 + kb * 8;
        int nc = K1 >> 6;
        for (int kc = 0; kc < nc; kc++) {
            bf16x8 stg[4];
#pragma unroll
            for (int it = 0; it < 4; it++) {
                int o = it * 2048 + t * 8;
                int p = o >> 12, j = (o >> 9) & 7, rem = o & 511;
                int ge = ((kc * 2 + p) * 16 + 8 * bn + j) * 512 + rem;
                stg[it] = *(const bf16x8*)(B1frag + ge);
            }
            __syncthreads();
#pragma unroll
            for (int it = 0; it < 4; it++)
                *(bf16x8*)&bs[it * 2048 + t * 8] = stg[it];
            __syncthreads();
#pragma unroll
            for (int ks = 0; ks < 2; ks++) {
                int kk = kc * 64 + ks * 32;
                bf16x8 a0 = *(const bf16x8*)(ap0 + kk);
                bf16x8 a1 = *(const bf16x8*)(ap1 + kk);
#pragma unroll
                for (int ct = 0; ct < 8; ct++) {
                    bf16x8 bf = *(const bf16x8*)&bs[ks * 4096 + ct * 512 + lane * 8];
                    acc[0][ct] = __builtin_amdgcn_mfma_f32_16x16x32_bf16(a0, bf, acc[0][ct], 0, 0, 0);
                    acc[1][ct] = __builtin_amdgcn_mfma_f32_16x16x32_bf16(a1, bf, acc[1][ct], 0, 0, 0);
                }
            }
        }
    }

    // ---- epilogue: bias, store bf16, BN stats ----
    bool dostats = (colsum != nullptr);
    if (dostats) {
        if (t < 128) { lsum[t] = 0.f; lsq[t] = 0.f; }
        __syncthreads();
    }
#pragma unroll
    for (int rf = 0; rf < 2; rf++) {
        int rbase = rowbase + rf * 16 + kb * 4;
#pragma unroll
        for (int ct = 0; ct < 8; ct++) {
            int col = bn * 128 + ct * 16 + n;
            float bv = bias ? bias[col] : 0.f;
            float ps = 0.f, pq = 0.f;
#pragma unroll
            for (int r = 0; r < 4; r++) {
                int gm = rbase + r;
                if (gm < M) {
                    float v = acc[rf][ct][r] + bv;
                    C[(size_t)gm * 256 + col] = (__bf16)v;
                    ps += v; pq += v * v;
                }
            }
            if (dostats) {
                ps += __shfl_xor(ps, 16, 64); pq += __shfl_xor(pq, 16, 64);
                ps += __shfl_xor(ps, 32, 64); pq += __shfl_xor(pq, 32, 64);
                if (lane < 16) {
                    atomicAdd(&lsum[ct * 16 + n], ps);
                    atomicAdd(&lsq[ct * 16 + n], pq);
                }
            }
        }
    }
    if (dostats) {
        __syncthreads();
        if (t < 128) {
            atomicAdd(&colsum[bn * 128 + t], lsum[t]);
            atomicAdd(&colsq[bn * 128 + t], lsq[t]);
        }
    }
}

// ---------------------------------------------------------------------------
// BN apply (+relu) bf16->bf16, and final BN+residual+relu bf16->fp32.
// ---------------------------------------------------------------------------
__device__ __forceinline__ float bn1c(float v, float s, float q, float g, float b) {
    const float invn = 1.0f / (float)NN;
    float mu = s * invn;
    float var = q * invn - mu * mu;
    float r = rsqrtf(var + EPSF);
    return (v - mu) * r * g + b;
}

__global__ __launch_bounds__(256) void bn_relu_kernel(
    const __bf16* __restrict__ h, const float* __restrict__ stats,
    const float* __restrict__ g, const float* __restrict__ b, __bf16* __restrict__ o)
{
    size_t idx = (size_t)blockIdx.x * 256 + threadIdx.x;
    int j = ((int)idx & 31) * 8;
    bf16x8 v = ((const bf16x8*)h)[idx];
    bf16x8 r;
#pragma unroll
    for (int u = 0; u < 8; u++)
        r[u] = (__bf16)fmaxf(bn1c((float)v[u], stats[j + u], stats[256 + j + u], g[j + u], b[j + u]), 0.f);
    ((bf16x8*)o)[idx] = r;
}

__global__ __launch_bounds__(256) void final_kernel(
    const __bf16* __restrict__ h2, const float* __restrict__ stats,
    const float* __restrict__ g, const float* __restrict__ b,
    const __bf16* __restrict__ resb, float* __restrict__ o)
{
    size_t idx = (size_t)blockIdx.x * 256 + threadIdx.x;
    int j = ((int)idx & 31) * 8;
    bf16x8 v = ((const bf16x8*)h2)[idx];
    bf16x8 rr = ((const bf16x8*)resb)[idx];
    float r[8];
#pragma unroll
    for (int u = 0; u < 8; u++)
        r[u] = fmaxf(bn1c((float)v[u], stats[j + u], stats[256 + j + u], g[j + u], b[j + u]) + (float)rr[u], 0.f);
    float4 o0 = {r[0], r[1], r[2], r[3]}, o1 = {r[4], r[5], r[6], r[7]};
    ((float4*)o)[idx * 2 + 0] = o0;
    ((float4*)o)[idx * 2 + 1] = o1;
}

// ---------------------------------------------------------------------------
extern "C" void kernel_launch(void* const* d_in, const int* in_sizes, int n_in,
                              void* d_out, int out_size, void* d_ws, size_t ws_size,
                              hipStream_t stream)
{
    (void)in_sizes; (void)n_in; (void)out_size; (void)ws_size;
    const float* x    = (const float*)d_in[0];
    const float* wid  = (const float*)d_in[1];
    const int*   widx = (const int*)d_in[2];
    const float* m1w1 = (const float*)d_in[4];
    const float* m1b1 = (const float*)d_in[5];
    const float* m1w2 = (const float*)d_in[6];
    const float* m1b2 = (const float*)d_in[7];
    const float* m2w1 = (const float*)d_in[8];
    const float* m2b1 = (const float*)d_in[9];
    const float* m2w2 = (const float*)d_in[10];
    const float* m2b2 = (const float*)d_in[11];
    const float* fc1w = (const float*)d_in[12];
    const float* fc1b = (const float*)d_in[13];
    const float* bn1g = (const float*)d_in[14];
    const float* bn1b = (const float*)d_in[15];
    const float* fc2w = (const float*)d_in[16];
    const float* fc2b = (const float*)d_in[17];
    const float* bn2g = (const float*)d_in[18];
    const float* bn2b = (const float*)d_in[19];
    const float* resw = (const float*)d_in[20];
    float* out = (float*)d_out;

    char* ws = (char*)d_ws;
    __bf16* xbf   = (__bf16*)(ws);                    // 12.8 MB
    int2*   perm  = (int2*)(ws + 12800000);           // 6.4 MB
    float2* v12   = (float2*)(ws + 19200000);         // 6.4 MB
    __bf16* agg1s = (__bf16*)(ws + 25600000);         // [NN,256] 25.6 MB
    __bf16* agg2s = (__bf16*)(ws + 51200000);         // [NN,512] 51.2 MB
    __bf16* h1    = (__bf16*)(ws + 102400000);        // 25.6 MB (h2 overlay)
    __bf16* h2    = h1;
    __bf16* hbn   = (__bf16*)(ws + 128000000);        // 25.6 MB
    __bf16* resb  = (__bf16*)(ws + 153600000);        // 25.6 MB
    const size_t offS = 179200000;
    int* row_start = (int*)(ws + offS);               // 200064 B
    int* cursor    = (int*)(ws + offS + 200064);      // 200064 B
    int* blksum    = (int*)(ws + offS + 400128);
    int* blkoff    = (int*)(ws + offS + 401152);
    float* stats   = (float*)(ws + offS + 402176);    // 1024 floats
    __bf16* efrag    = (__bf16*)(ws + offS + 406272);   // 16 KB
    __bf16* bfrag1a  = (__bf16*)(ws + offS + 422656);   // 128*256*2 = 64 KB
    __bf16* bfrag1bc = (__bf16*)(ws + offS + 488192);   // 256*256*2 = 128 KB
    __bf16* bfrag2a  = (__bf16*)(ws + offS + 619264);   // 256*256*2 = 128 KB
    __bf16* bfrag2bc = (__bf16*)(ws + offS + 750336);   // 512*256*2 = 256 KB
    __bf16* bfragR   = (__bf16*)(ws + offS + 1012480);  // 128*256*2 = 64 KB

    dim3 b256(256);
    dim3 ggrid((NN + GBM - 1) / GBM, 2);

    // 0) conversions / weight packing
    cvt_bf16_kernel<<<3125, b256, 0, stream>>>(x, xbf, NN * FIN / 8);
    prep_w_kernel<<<32, b256, 0, stream>>>(m1w1, m2w1, efrag);
    prep_b_kernel<<<128, b256, 0, stream>>>(fc1w, bfrag1a, 128);
    prep_b_kernel<<<256, b256, 0, stream>>>(fc1w + 128 * 256, bfrag1bc, 256);
    prep_b_kernel<<<256, b256, 0, stream>>>(fc2w, bfrag2a, 256);
    prep_b_kernel<<<512, b256, 0, stream>>>(fc2w + 256 * 256, bfrag2bc, 512);
    prep_b_kernel<<<128, b256, 0, stream>>>(resw, bfragR, 128);

    // 1) CSR build (indices only)
    hipMemsetAsync(cursor, 0, NN * 4, stream);
    hist_kernel<<<NE / 256, b256, 0, stream>>>(widx, cursor);
    scan1_kernel<<<NCHUNK, b256, 0, stream>>>(cursor, blksum);
    scan2_kernel<<<1, b256, 0, stream>>>(blksum, blkoff);
    scan3_kernel<<<NCHUNK, b256, 0, stream>>>(cursor, blkoff, row_start);
    hipMemsetAsync(cursor, 0, NN * 4, stream);
    fill_kernel<<<NE / 256, b256, 0, stream>>>(widx, widx + NE, row_start, cursor, perm);

    // 2) edge MLP over CSR order -> v12
    edge_mlp_mfma<<<1024, b256, 0, stream>>>(xbf, perm, efrag,
        m1b1, m1w2, m1b2, m2b1, m2w2, m2b2, v12);

    // 3) conv1
    spmm1_kernel<<<NN / 4, b256, 0, stream>>>(xbf, perm, v12, row_start, agg1s);
    hipMemsetAsync(stats, 0, 1024 * 4, stream);
    gemm_mfma<<<ggrid, b256, 0, stream>>>(xbf, bfrag1a, 128, wid,
        agg1s, bfrag1bc, 256, fc1b, h1, NN, stats, stats + 256);
    bn_relu_kernel<<<NN * FOUT / 8 / 256, b256, 0, stream>>>(h1, stats, bn1g, bn1b, hbn);

    // 4) conv2 + residual
    spmm2_kernel<<<NN / 4, b256, 0, stream>>>(hbn, perm, v12, row_start, agg2s);
    gemm_mfma<<<ggrid, b256, 0, stream>>>(hbn, bfrag2a, 256, wid,
        agg2s, bfrag2bc, 512, fc2b, h2, NN, stats + 512, stats + 768);
    gemm_mfma<<<ggrid, b256, 0, stream>>>(xbf, bfragR, 128, nullptr,
        nullptr, nullptr, 0, nullptr, resb, NN, nullptr, nullptr);
    final_kernel<<<NN * FOUT / 8 / 256, b256, 0, stream>>>(h2, stats + 512, bn2g, bn2b, resb, out);
}

// Round 6
// 468.384 us; speedup vs baseline: 3.2686x; 1.1497x over previous
//
#include <hip/hip_runtime.h>
#include <hip/hip_bf16.h>
#include <math.h>

#define NN 50000
#define NE 800000
#define FIN 128
#define FOUT 256
#define EPSF 1e-5f
#define NCHUNK 196  // ceil(NN/256)

typedef __bf16 bf16x8 __attribute__((ext_vector_type(8)));
typedef __bf16 bf16x4 __attribute__((ext_vector_type(4)));
typedef __bf16 bf16x2 __attribute__((ext_vector_type(2)));
typedef float f32x4 __attribute__((ext_vector_type(4)));

// ---------------------------------------------------------------------------
// fp32 -> bf16 convert (8 elems/thread)
// ---------------------------------------------------------------------------
__global__ void cvt_bf16_kernel(const float* __restrict__ in, __bf16* __restrict__ out, int n8) {
    int idx = blockIdx.x * 256 + threadIdx.x;
    if (idx >= n8) return;
    float4 a = ((const float4*)in)[idx * 2 + 0];
    float4 b = ((const float4*)in)[idx * 2 + 1];
    bf16x8 v = {(__bf16)a.x, (__bf16)a.y, (__bf16)a.z, (__bf16)a.w,
                (__bf16)b.x, (__bf16)b.y, (__bf16)b.z, (__bf16)b.w};
    ((bf16x8*)out)[idx] = v;
}

// ---------------------------------------------------------------------------
// Pack dense B [K x 256] fp32 row-major into MFMA B-fragment order bf16:
// frag[((kk*16+ct)*64+l)*8+i] = B[kk*32+(l>>4)*8+i][ct*16+(l&15)]
// ---------------------------------------------------------------------------
__global__ void prep_b_kernel(const float* __restrict__ B, __bf16* __restrict__ frag, int K) {
    int idx = blockIdx.x * 256 + threadIdx.x;
    if (idx >= K * 256) return;
    int i = idx & 7, l = (idx >> 3) & 63, ct = (idx >> 9) & 15, kk = idx >> 13;
    int k = kk * 32 + (l >> 4) * 8 + i;
    int c = ct * 16 + (l & 15);
    frag[idx] = (__bf16)B[k * 256 + c];
}

// ---------------------------------------------------------------------------
// Pack combined edge-MLP weights W1 [128k x 64c] (cols 0..31=mlp1, 32..63=mlp2)
// ---------------------------------------------------------------------------
__global__ void prep_w_kernel(const float* __restrict__ w1a, const float* __restrict__ w1b,
                              __bf16* __restrict__ fragbuf)
{
    int idx = blockIdx.x * 256 + threadIdx.x;  // 8192 total
    if (idx >= 8192) return;
    int i = idx & 7, l = (idx >> 3) & 63, ct = (idx >> 9) & 3, kt = idx >> 11;
    int n = l & 15, kb = l >> 4;
    int k = kt * 32 + kb * 8 + i;
    int c = ct * 16 + n;
    float w = (c < 32) ? w1a[k * 32 + c] : w1b[k * 32 + (c - 32)];
    fragbuf[idx] = (__bf16)w;
}

// ---------------------------------------------------------------------------
// CSR build: histogram, 3-kernel exclusive scan, fill (col,row) int2.
// ---------------------------------------------------------------------------
__global__ void hist_kernel(const int* __restrict__ rowi, int* __restrict__ counts) {
    int e = blockIdx.x * 256 + threadIdx.x;
    if (e < NE) atomicAdd(&counts[rowi[e]], 1);
}

__global__ void scan1_kernel(const int* __restrict__ counts, int* __restrict__ blksum) {
    __shared__ int s[256];
    int t = threadIdx.x, idx = blockIdx.x * 256 + t;
    s[t] = (idx < NN) ? counts[idx] : 0;
    __syncthreads();
    for (int off = 128; off > 0; off >>= 1) {
        if (t < off) s[t] += s[t + off];
        __syncthreads();
    }
    if (t == 0) blksum[blockIdx.x] = s[0];
}

__global__ void scan2_kernel(const int* __restrict__ blksum, int* __restrict__ blkoff) {
    __shared__ int s[256];
    int t = threadIdx.x;
    int v = (t < NCHUNK) ? blksum[t] : 0;
    s[t] = v; __syncthreads();
    for (int off = 1; off < 256; off <<= 1) {
        int xv = (t >= off) ? s[t - off] : 0;
        __syncthreads();
        s[t] += xv;
        __syncthreads();
    }
    if (t < NCHUNK) blkoff[t] = s[t] - v;  // exclusive
}

__global__ void scan3_kernel(const int* __restrict__ counts, const int* __restrict__ blkoff,
                             int* __restrict__ row_start) {
    __shared__ int s[256];
    int t = threadIdx.x, idx = blockIdx.x * 256 + t;
    int v = (idx < NN) ? counts[idx] : 0;
    s[t] = v; __syncthreads();
    for (int off = 1; off < 256; off <<= 1) {
        int xv = (t >= off) ? s[t - off] : 0;
        __syncthreads();
        s[t] += xv;
        __syncthreads();
    }
    if (idx <= NN) row_start[idx] = s[t] - v + blkoff[blockIdx.x];
}

__global__ void fill_kernel(const int* __restrict__ rowi, const int* __restrict__ coli,
                            const int* __restrict__ row_start, int* __restrict__ cursor,
                            int2* __restrict__ perm) {
    int e = blockIdx.x * 256 + threadIdx.x;
    if (e >= NE) return;
    int r = rowi[e];
    int p = row_start[r] + atomicAdd(&cursor[r], 1);
    perm[p] = make_int2(coli[e], r);
}

// ---------------------------------------------------------------------------
// Edge MLP via MFMA over CSR-ordered edges (row gathers ~cache-hits).
// 16 edges per wave-iter; writes v12[p] = (v1,v2) at CSR position.
// ---------------------------------------------------------------------------
__global__ __launch_bounds__(256) void edge_mlp_mfma(
    const __bf16* __restrict__ x, const int2* __restrict__ perm,
    const __bf16* __restrict__ fragbuf,
    const float* __restrict__ b1a, const float* __restrict__ w2a, const float* __restrict__ b2a,
    const float* __restrict__ b1b, const float* __restrict__ w2b, const float* __restrict__ b2b,
    float2* __restrict__ v12)
{
    int lane = threadIdx.x & 63;
    int gwave = (blockIdx.x * 256 + threadIdx.x) >> 6;
    int nwaves = (gridDim.x * 256) >> 6;

    bf16x8 bfrag[4][4];
    const bf16x8* fb = (const bf16x8*)fragbuf;
#pragma unroll
    for (int kt = 0; kt < 4; kt++)
#pragma unroll
        for (int ct = 0; ct < 4; ct++)
            bfrag[kt][ct] = fb[(kt * 4 + ct) * 64 + lane];

    int n = lane & 15;
    int kb = lane >> 4;
    float b1c[4], w2c[4];
#pragma unroll
    for (int ct = 0; ct < 4; ct++) {
        int c = ct * 16 + n;
        b1c[ct] = (c < 32) ? b1a[c] : b1b[c - 32];
        w2c[ct] = (c < 32) ? w2a[c] : w2b[c - 32];
    }
    float bias2a = b2a[0], bias2b = b2b[0];

    const int ngroups = NE / 16;
    for (int g = gwave; g < ngroups; g += nwaves) {
        int2 pe = perm[g * 16 + n];
        const __bf16* xr = x + (size_t)pe.y * FIN + kb * 8;
        const __bf16* xc = x + (size_t)pe.x * FIN + kb * 8;
        f32x4 acc[4] = {{0.f, 0.f, 0.f, 0.f}, {0.f, 0.f, 0.f, 0.f},
                        {0.f, 0.f, 0.f, 0.f}, {0.f, 0.f, 0.f, 0.f}};
#pragma unroll
        for (int kt = 0; kt < 4; kt++) {
            bf16x8 a = *(const bf16x8*)(xr + kt * 32);
            bf16x8 c = *(const bf16x8*)(xc + kt * 32);
            bf16x8 af;
#pragma unroll
            for (int i = 0; i < 8; i++)
                af[i] = (__bf16)fabsf((float)a[i] - (float)c[i]);
#pragma unroll
            for (int ct = 0; ct < 4; ct++)
                acc[ct] = __builtin_amdgcn_mfma_f32_16x16x32_bf16(af, bfrag[kt][ct], acc[ct], 0, 0, 0);
        }
        float p1[4], p2[4];
#pragma unroll
        for (int r = 0; r < 4; r++) {
            float h0 = fmaxf(acc[0][r] + b1c[0], 0.f) * w2c[0];
            float h1 = fmaxf(acc[1][r] + b1c[1], 0.f) * w2c[1];
            float h2 = fmaxf(acc[2][r] + b1c[2], 0.f) * w2c[2];
            float h3 = fmaxf(acc[3][r] + b1c[3], 0.f) * w2c[3];
            p1[r] = h0 + h1;
            p2[r] = h2 + h3;
        }
#pragma unroll
        for (int off = 1; off < 16; off <<= 1)
#pragma unroll
            for (int r = 0; r < 4; r++) {
                p1[r] += __shfl_xor(p1[r], off, 64);
                p2[r] += __shfl_xor(p2[r], off, 64);
            }
        if (n == 0) {
#pragma unroll
            for (int r = 0; r < 4; r++) {
                int p = g * 16 + kb * 4 + r;
                v12[p] = make_float2(1.f / (1.f + expf(-(p1[r] + bias2a))),
                                     1.f / (1.f + expf(-(p2[r] + bias2b))));
            }
        }
    }
}

// ---------------------------------------------------------------------------
// spmm: one wave per node; 4x-unrolled gather loop (4 row-loads in flight).
// ---------------------------------------------------------------------------
__global__ __launch_bounds__(256) void spmm1_kernel(
    const __bf16* __restrict__ x, const int2* __restrict__ perm,
    const float2* __restrict__ v12, const int* __restrict__ row_start,
    __bf16* __restrict__ agg)
{
    int lane = threadIdx.x & 63;
    int i = blockIdx.x * 4 + (threadIdx.x >> 6);
    if (i >= NN) return;
    int f0 = lane * 2;
    float a1x = 0, a1y = 0, a2x = 0, a2y = 0;
    int p0 = row_start[i], p1 = row_start[i + 1];
    int p = p0;
    for (; p + 4 <= p1; p += 4) {
        int cc[4]; float2 vv[4]; bf16x2 ff[4];
#pragma unroll
        for (int u = 0; u < 4; u++) { cc[u] = perm[p + u].x; vv[u] = v12[p + u]; }
#pragma unroll
        for (int u = 0; u < 4; u++)
            ff[u] = *(const bf16x2*)(x + (size_t)cc[u] * FIN + f0);
#pragma unroll
        for (int u = 0; u < 4; u++) {
            float fx = (float)ff[u][0], fy = (float)ff[u][1];
            a1x += vv[u].x * fx; a1y += vv[u].x * fy;
            a2x += vv[u].y * fx; a2y += vv[u].y * fy;
        }
    }
    for (; p < p1; p++) {
        int c = perm[p].x;
        float2 vv = v12[p];
        bf16x2 f = *(const bf16x2*)(x + (size_t)c * FIN + f0);
        float fx = (float)f[0], fy = (float)f[1];
        a1x += vv.x * fx; a1y += vv.x * fy;
        a2x += vv.y * fx; a2y += vv.y * fy;
    }
    __bf16* ag = agg + (size_t)i * 256;
    *(bf16x2*)(ag + f0) = (bf16x2){(__bf16)a1x, (__bf16)a1y};
    *(bf16x2*)(ag + FIN + f0) = (bf16x2){(__bf16)a2x, (__bf16)a2y};
}

__global__ __launch_bounds__(256) void spmm2_kernel(
    const __bf16* __restrict__ h, const int2* __restrict__ perm,
    const float2* __restrict__ v12, const int* __restrict__ row_start,
    __bf16* __restrict__ agg)
{
    int lane = threadIdx.x & 63;
    int i = blockIdx.x * 4 + (threadIdx.x >> 6);
    if (i >= NN) return;
    int f0 = lane * 4;
    float s1x = 0, s1y = 0, s1z = 0, s1w = 0, s2x = 0, s2y = 0, s2z = 0, s2w = 0;
    int p0 = row_start[i], p1 = row_start[i + 1];
    int p = p0;
    for (; p + 4 <= p1; p += 4) {
        int cc[4]; float2 vv[4]; bf16x4 ff[4];
#pragma unroll
        for (int u = 0; u < 4; u++) { cc[u] = perm[p + u].x; vv[u] = v12[p + u]; }
#pragma unroll
        for (int u = 0; u < 4; u++)
            ff[u] = *(const bf16x4*)(h + (size_t)cc[u] * FOUT + f0);
#pragma unroll
        for (int u = 0; u < 4; u++) {
            float fx = (float)ff[u][0], fy = (float)ff[u][1];
            float fz = (float)ff[u][2], fw = (float)ff[u][3];
            s1x += vv[u].x * fx; s1y += vv[u].x * fy; s1z += vv[u].x * fz; s1w += vv[u].x * fw;
            s2x += vv[u].y * fx; s2y += vv[u].y * fy; s2z += vv[u].y * fz; s2w += vv[u].y * fw;
        }
    }
    for (; p < p1; p++) {
        int c = perm[p].x;
        float2 vv = v12[p];
        bf16x4 f = *(const bf16x4*)(h + (size_t)c * FOUT + f0);
        float fx = (float)f[0], fy = (float)f[1], fz = (float)f[2], fw = (float)f[3];
        s1x += vv.x * fx; s1y += vv.x * fy; s1z += vv.x * fz; s1w += vv.x * fw;
        s2x += vv.y * fx; s2y += vv.y * fy; s2z += vv.y * fz; s2w += vv.y * fw;
    }
    __bf16* ag = agg + (size_t)i * 512;
    *(bf16x4*)(ag + f0) = (bf16x4){(__bf16)s1x, (__bf16)s1y, (__bf16)s1z, (__bf16)s1w};
    *(bf16x4*)(ag + FOUT + f0) = (bf16x4){(__bf16)s2x, (__bf16)s2y, (__bf16)s2z, (__bf16)s2w};
}

// ---------------------------------------------------------------------------
// Two-piece bf16 MFMA GEMM, LDS-staged B:
//   C = [wid ⊙] (A2[M,K2] @ B2) [+ A1[M,K1] @ B1] (+bias) (+BN col stats)
// Grid (ceil(M/128), 2); 4 waves; wave = 32 rows x 128 cols; C bf16.
// ---------------------------------------------------------------------------
#define GBM 128
__global__ __launch_bounds__(256) void gemm_mfma(
    const __bf16* __restrict__ A2, const __bf16* __restrict__ B2frag, int K2,
    const float* __restrict__ wid,
    const __bf16* __restrict__ A1, const __bf16* __restrict__ B1frag, int K1,
    const float* __restrict__ bias, __bf16* __restrict__ C, int M,
    float* __restrict__ colsum, float* __restrict__ colsq)
{
    __shared__ __bf16 bs[8192];     // 16KB chunk
    __shared__ float lsum[128], lsq[128];
    int t = threadIdx.x, lane = t & 63, w = t >> 6;
    int bn = blockIdx.y;
    int n = lane & 15, kb = lane >> 4;
    int rowbase = blockIdx.x * GBM + w * 32;
    int r0 = rowbase + n;      if (r0 > M - 1) r0 = M - 1;
    int r1 = rowbase + 16 + n; if (r1 > M - 1) r1 = M - 1;

    f32x4 acc[2][8];
#pragma unroll
    for (int rf = 0; rf < 2; rf++)
#pragma unroll
        for (int ct = 0; ct < 8; ct++) acc[rf][ct] = (f32x4){0.f, 0.f, 0.f, 0.f};

    // ---- phase A2 @ B2 ----
    {
        const __bf16* ap0 = A2 + (size_t)r0 * K2 + kb * 8;
        const __bf16* ap1 = A2 + (size_t)r1 * K2 + kb * 8;
        int nc = K2 >> 6;
        for (int kc = 0; kc < nc; kc++) {
            bf16x8 stg[4];
#pragma unroll
            for (int it = 0; it < 4; it++) {
                int o = it * 2048 + t * 8;
                int p = o >> 12, j = (o >> 9) & 7, rem = o & 511;
                int ge = ((kc * 2 + p) * 16 + 8 * bn + j) * 512 + rem;
                stg[it] = *(const bf16x8*)(B2frag + ge);
            }
            __syncthreads();
#pragma unroll
            for (int it = 0; it < 4; it++)
                *(bf16x8*)&bs[it * 2048 + t * 8] = stg[it];
            __syncthreads();
#pragma unroll
            for (int ks = 0; ks < 2; ks++) {
                int kk = kc * 64 + ks * 32;
                bf16x8 a0 = *(const bf16x8*)(ap0 + kk);
                bf16x8 a1 = *(const bf16x8*)(ap1 + kk);
#pragma unroll
                for (int ct = 0; ct < 8; ct++) {
                    bf16x8 bf = *(const bf16x8*)&bs[ks * 4096 + ct * 512 + lane * 8];
                    acc[0][ct] = __builtin_amdgcn_mfma_f32_16x16x32_bf16(a0, bf, acc[0][ct], 0, 0, 0);
                    acc[1][ct] = __builtin_amdgcn_mfma_f32_16x16x32_bf16(a1, bf, acc[1][ct], 0, 0, 0);
                }
            }
        }
    }

    // ---- per-row wid scale of the A2 partial ----
    if (wid) {
#pragma unroll
        for (int rf = 0; rf < 2; rf++) {
            int rb = rowbase + rf * 16 + kb * 4;
            float w4[4];
#pragma unroll
            for (int r = 0; r < 4; r++) {
                int gm = rb + r; if (gm > M - 1) gm = M - 1;
                w4[r] = wid[gm];
            }
#pragma unroll
            for (int ct = 0; ct < 8; ct++)
#pragma unroll
                for (int r = 0; r < 4; r++) acc[rf][ct][r] *= w4[r];
        }
    }

    // ---- phase A1 @ B1 ----
    if (A1) {
        const __bf16* ap0 = A1 + (size_t)r0 * K1 + kb * 8;
        const __bf16* ap1 = A1 + (size_t)r1 * K1 + kb * 8;
        int nc = K1 >> 6;
        for (int kc = 0; kc < nc; kc++) {
            bf16x8 stg[4];
#pragma unroll
            for (int it = 0; it < 4; it++) {
                int o = it * 2048 + t * 8;
                int p = o >> 12, j = (o >> 9) & 7, rem = o & 511;
                int ge = ((kc * 2 + p) * 16 + 8 * bn + j) * 512 + rem;
                stg[it] = *(const bf16x8*)(B1frag + ge);
            }
            __syncthreads();
#pragma unroll
            for (int it = 0; it < 4; it++)
                *(bf16x8*)&bs[it * 2048 + t * 8] = stg[it];
            __syncthreads();
#pragma unroll
            for (int ks = 0; ks < 2; ks++) {
                int kk = kc * 64 + ks * 32;
                bf16x8 a0 = *(const bf16x8*)(ap0 + kk);
                bf16x8 a1 = *(const bf16x8*)(ap1 + kk);
#pragma unroll
                for (int ct = 0; ct < 8; ct++) {
                    bf16x8 bf = *(const bf16x8*)&bs[ks * 4096 + ct * 512 + lane * 8];
                    acc[0][ct] = __builtin_amdgcn_mfma_f32_16x16x32_bf16(a0, bf, acc[0][ct], 0, 0, 0);
                    acc[1][ct] = __builtin_amdgcn_mfma_f32_16x16x32_bf16(a1, bf, acc[1][ct], 0, 0, 0);
                }
            }
        }
    }

    // ---- epilogue: bias, store bf16, BN stats ----
    bool dostats = (colsum != nullptr);
    if (dostats) {
        if (t < 128) { lsum[t] = 0.f; lsq[t] = 0.f; }
        __syncthreads();
    }
#pragma unroll
    for (int rf = 0; rf < 2; rf++) {
        int rbase = rowbase + rf * 16 + kb * 4;
#pragma unroll
        for (int ct = 0; ct < 8; ct++) {
            int col = bn * 128 + ct * 16 + n;
            float bv = bias ? bias[col] : 0.f;
            float ps = 0.f, pq = 0.f;
#pragma unroll
            for (int r = 0; r < 4; r++) {
                int gm = rbase + r;
                if (gm < M) {
                    float v = acc[rf][ct][r] + bv;
                    C[(size_t)gm * 256 + col] = (__bf16)v;
                    ps += v; pq += v * v;
                }
            }
            if (dostats) {
                ps += __shfl_xor(ps, 16, 64); pq += __shfl_xor(pq, 16, 64);
                ps += __shfl_xor(ps, 32, 64); pq += __shfl_xor(pq, 32, 64);
                if (lane < 16) {
                    atomicAdd(&lsum[ct * 16 + n], ps);
                    atomicAdd(&lsq[ct * 16 + n], pq);
                }
            }
        }
    }
    if (dostats) {
        __syncthreads();
        if (t < 128) {
            atomicAdd(&colsum[bn * 128 + t], lsum[t]);
            atomicAdd(&colsq[bn * 128 + t], lsq[t]);
        }
    }
}

// ---------------------------------------------------------------------------
// BN apply (+relu) bf16->bf16, and final BN+residual+relu bf16->fp32.
// ---------------------------------------------------------------------------
__device__ __forceinline__ float bn1c(float v, float s, float q, float g, float b) {
    const float invn = 1.0f / (float)NN;
    float mu = s * invn;
    float var = q * invn - mu * mu;
    float r = rsqrtf(var + EPSF);
    return (v - mu) * r * g + b;
}

__global__ __launch_bounds__(256) void bn_relu_kernel(
    const __bf16* __restrict__ h, const float* __restrict__ stats,
    const float* __restrict__ g, const float* __restrict__ b, __bf16* __restrict__ o)
{
    size_t idx = (size_t)blockIdx.x * 256 + threadIdx.x;
    int j = ((int)idx & 31) * 8;
    bf16x8 v = ((const bf16x8*)h)[idx];
    bf16x8 r;
#pragma unroll
    for (int u = 0; u < 8; u++)
        r[u] = (__bf16)fmaxf(bn1c((float)v[u], stats[j + u], stats[256 + j + u], g[j + u], b[j + u]), 0.f);
    ((bf16x8*)o)[idx] = r;
}

__global__ __launch_bounds__(256) void final_kernel(
    const __bf16* __restrict__ h2, const float* __restrict__ stats,
    const float* __restrict__ g, const float* __restrict__ b,
    const __bf16* __restrict__ resb, float* __restrict__ o)
{
    size_t idx = (size_t)blockIdx.x * 256 + threadIdx.x;
    int j = ((int)idx & 31) * 8;
    bf16x8 v = ((const bf16x8*)h2)[idx];
    bf16x8 rr = ((const bf16x8*)resb)[idx];
    float r[8];
#pragma unroll
    for (int u = 0; u < 8; u++)
        r[u] = fmaxf(bn1c((float)v[u], stats[j + u], stats[256 + j + u], g[j + u], b[j + u]) + (float)rr[u], 0.f);
    float4 o0 = {r[0], r[1], r[2], r[3]}, o1 = {r[4], r[5], r[6], r[7]};
    ((float4*)o)[idx * 2 + 0] = o0;
    ((float4*)o)[idx * 2 + 1] = o1;
}

// ---------------------------------------------------------------------------
extern "C" void kernel_launch(void* const* d_in, const int* in_sizes, int n_in,
                              void* d_out, int out_size, void* d_ws, size_t ws_size,
                              hipStream_t stream)
{
    (void)in_sizes; (void)n_in; (void)out_size; (void)ws_size;
    const float* x    = (const float*)d_in[0];
    const float* wid  = (const float*)d_in[1];
    const int*   widx = (const int*)d_in[2];
    const float* m1w1 = (const float*)d_in[4];
    const float* m1b1 = (const float*)d_in[5];
    const float* m1w2 = (const float*)d_in[6];
    const float* m1b2 = (const float*)d_in[7];
    const float* m2w1 = (const float*)d_in[8];
    const float* m2b1 = (const float*)d_in[9];
    const float* m2w2 = (const float*)d_in[10];
    const float* m2b2 = (const float*)d_in[11];
    const float* fc1w = (const float*)d_in[12];
    const float* fc1b = (const float*)d_in[13];
    const float* bn1g = (const float*)d_in[14];
    const float* bn1b = (const float*)d_in[15];
    const float* fc2w = (const float*)d_in[16];
    const float* fc2b = (const float*)d_in[17];
    const float* bn2g = (const float*)d_in[18];
    const float* bn2b = (const float*)d_in[19];
    const float* resw = (const float*)d_in[20];
    float* out = (float*)d_out;

    char* ws = (char*)d_ws;
    __bf16* xbf   = (__bf16*)(ws);                    // 12.8 MB
    int2*   perm  = (int2*)(ws + 12800000);           // 6.4 MB
    float2* v12   = (float2*)(ws + 19200000);         // 6.4 MB
    __bf16* agg1s = (__bf16*)(ws + 25600000);         // [NN,256] 25.6 MB
    __bf16* agg2s = (__bf16*)(ws + 51200000);         // [NN,512] 51.2 MB
    __bf16* h1    = (__bf16*)(ws + 102400000);        // 25.6 MB (h2 overlay)
    __bf16* h2    = h1;
    __bf16* hbn   = (__bf16*)(ws + 128000000);        // 25.6 MB
    __bf16* resb  = (__bf16*)(ws + 153600000);        // 25.6 MB
    const size_t offS = 179200000;
    int* row_start = (int*)(ws + offS);               // 200064 B
    int* cursor    = (int*)(ws + offS + 200064);      // 200064 B
    int* blksum    = (int*)(ws + offS + 400128);
    int* blkoff    = (int*)(ws + offS + 401152);
    float* stats   = (float*)(ws + offS + 402176);    // 1024 floats
    __bf16* efrag    = (__bf16*)(ws + offS + 406272);   // 16 KB
    __bf16* bfrag1a  = (__bf16*)(ws + offS + 422656);   // 128*256*2 = 64 KB
    __bf16* bfrag1bc = (__bf16*)(ws + offS + 488192);   // 256*256*2 = 128 KB
    __bf16* bfrag2a  = (__bf16*)(ws + offS + 619264);   // 256*256*2 = 128 KB
    __bf16* bfrag2bc = (__bf16*)(ws + offS + 750336);   // 512*256*2 = 256 KB
    __bf16* bfragR   = (__bf16*)(ws + offS + 1012480);  // 128*256*2 = 64 KB

    dim3 b256(256);
    dim3 ggrid((NN + GBM - 1) / GBM, 2);

    // 0) conversions / weight packing
    cvt_bf16_kernel<<<3125, b256, 0, stream>>>(x, xbf, NN * FIN / 8);
    prep_w_kernel<<<32, b256, 0, stream>>>(m1w1, m2w1, efrag);
    prep_b_kernel<<<128, b256, 0, stream>>>(fc1w, bfrag1a, 128);
    prep_b_kernel<<<256, b256, 0, stream>>>(fc1w + 128 * 256, bfrag1bc, 256);
    prep_b_kernel<<<256, b256, 0, stream>>>(fc2w, bfrag2a, 256);
    prep_b_kernel<<<512, b256, 0, stream>>>(fc2w + 256 * 256, bfrag2bc, 512);
    prep_b_kernel<<<128, b256, 0, stream>>>(resw, bfragR, 128);

    // 1) CSR build (indices only)
    hipMemsetAsync(cursor, 0, NN * 4, stream);
    hist_kernel<<<NE / 256, b256, 0, stream>>>(widx, cursor);
    scan1_kernel<<<NCHUNK, b256, 0, stream>>>(cursor, blksum);
    scan2_kernel<<<1, b256, 0, stream>>>(blksum, blkoff);
    scan3_kernel<<<NCHUNK, b256, 0, stream>>>(cursor, blkoff, row_start);
    hipMemsetAsync(cursor, 0, NN * 4, stream);
    fill_kernel<<<NE / 256, b256, 0, stream>>>(widx, widx + NE, row_start, cursor, perm);

    // 2) edge MLP over CSR order -> v12
    edge_mlp_mfma<<<1024, b256, 0, stream>>>(xbf, perm, efrag,
        m1b1, m1w2, m1b2, m2b1, m2w2, m2b2, v12);

    // 3) conv1
    spmm1_kernel<<<NN / 4, b256, 0, stream>>>(xbf, perm, v12, row_start, agg1s);
    hipMemsetAsync(stats, 0, 1024 * 4, stream);
    gemm_mfma<<<ggrid, b256, 0, stream>>>(xbf, bfrag1a, 128, wid,
        agg1s, bfrag1bc, 256, fc1b, h1, NN, stats, stats + 256);
    bn_relu_kernel<<<NN * FOUT / 8 / 256, b256, 0, stream>>>(h1, stats, bn1g, bn1b, hbn);

    // 4) conv2 + residual
    spmm2_kernel<<<NN / 4, b256, 0, stream>>>(hbn, perm, v12, row_start, agg2s);
    gemm_mfma<<<ggrid, b256, 0, stream>>>(hbn, bfrag2a, 256, wid,
        agg2s, bfrag2bc, 512, fc2b, h2, NN, stats + 512, stats + 768);
    gemm_mfma<<<ggrid, b256, 0, stream>>>(xbf, bfragR, 128, nullptr,
        nullptr, nullptr, 0, nullptr, resb, NN, nullptr, nullptr);
    final_kernel<<<NN * FOUT / 8 / 256, b256, 0, stream>>>(h2, stats + 512, bn2g, bn2b, resb, out);
}

// Round 7
// 461.594 us; speedup vs baseline: 3.3166x; 1.0147x over previous
//
#include <hip/hip_runtime.h>
#include <hip/hip_bf16.h>
#include <math.h>

#define NN 50000
#define NE 800000
#define FIN 128
#define FOUT 256
#define EPSF 1e-5f
#define NCHUNK 196  // ceil(NN/256)

typedef __bf16 bf16x8 __attribute__((ext_vector_type(8)));
typedef __bf16 bf16x4 __attribute__((ext_vector_type(4)));
typedef __bf16 bf16x2 __attribute__((ext_vector_type(2)));
typedef float f32x4 __attribute__((ext_vector_type(4)));

// ---------------------------------------------------------------------------
// fp32 -> bf16 convert (8 elems/thread)
// ---------------------------------------------------------------------------
__global__ void cvt_bf16_kernel(const float* __restrict__ in, __bf16* __restrict__ out, int n8) {
    int idx = blockIdx.x * 256 + threadIdx.x;
    if (idx >= n8) return;
    float4 a = ((const float4*)in)[idx * 2 + 0];
    float4 b = ((const float4*)in)[idx * 2 + 1];
    bf16x8 v = {(__bf16)a.x, (__bf16)a.y, (__bf16)a.z, (__bf16)a.w,
                (__bf16)b.x, (__bf16)b.y, (__bf16)b.z, (__bf16)b.w};
    ((bf16x8*)out)[idx] = v;
}

// ---------------------------------------------------------------------------
// Pack dense B [K x 256] fp32 row-major into MFMA B-fragment order bf16:
// frag[((kk*16+ct)*64+l)*8+i] = B[kk*32+(l>>4)*8+i][ct*16+(l&15)]
// ---------------------------------------------------------------------------
__global__ void prep_b_kernel(const float* __restrict__ B, __bf16* __restrict__ frag, int K) {
    int idx = blockIdx.x * 256 + threadIdx.x;
    if (idx >= K * 256) return;
    int i = idx & 7, l = (idx >> 3) & 63, ct = (idx >> 9) & 15, kk = idx >> 13;
    int k = kk * 32 + (l >> 4) * 8 + i;
    int c = ct * 16 + (l & 15);
    frag[idx] = (__bf16)B[k * 256 + c];
}

// ---------------------------------------------------------------------------
// Pack combined edge-MLP weights W1 [128k x 64c] (cols 0..31=mlp1, 32..63=mlp2)
// ---------------------------------------------------------------------------
__global__ void prep_w_kernel(const float* __restrict__ w1a, const float* __restrict__ w1b,
                              __bf16* __restrict__ fragbuf)
{
    int idx = blockIdx.x * 256 + threadIdx.x;  // 8192 total
    if (idx >= 8192) return;
    int i = idx & 7, l = (idx >> 3) & 63, ct = (idx >> 9) & 3, kt = idx >> 11;
    int n = l & 15, kb = l >> 4;
    int k = kt * 32 + kb * 8 + i;
    int c = ct * 16 + n;
    float w = (c < 32) ? w1a[k * 32 + c] : w1b[k * 32 + (c - 32)];
    fragbuf[idx] = (__bf16)w;
}

// ---------------------------------------------------------------------------
// CSR build: histogram, 3-kernel exclusive scan, fill (col,row) int2.
// ---------------------------------------------------------------------------
__global__ void hist_kernel(const int* __restrict__ rowi, int* __restrict__ counts) {
    int e = blockIdx.x * 256 + threadIdx.x;
    if (e < NE) atomicAdd(&counts[rowi[e]], 1);
}

__global__ void scan1_kernel(const int* __restrict__ counts, int* __restrict__ blksum) {
    __shared__ int s[256];
    int t = threadIdx.x, idx = blockIdx.x * 256 + t;
    s[t] = (idx < NN) ? counts[idx] : 0;
    __syncthreads();
    for (int off = 128; off > 0; off >>= 1) {
        if (t < off) s[t] += s[t + off];
        __syncthreads();
    }
    if (t == 0) blksum[blockIdx.x] = s[0];
}

__global__ void scan2_kernel(const int* __restrict__ blksum, int* __restrict__ blkoff) {
    __shared__ int s[256];
    int t = threadIdx.x;
    int v = (t < NCHUNK) ? blksum[t] : 0;
    s[t] = v; __syncthreads();
    for (int off = 1; off < 256; off <<= 1) {
        int xv = (t >= off) ? s[t - off] : 0;
        __syncthreads();
        s[t] += xv;
        __syncthreads();
    }
    if (t < NCHUNK) blkoff[t] = s[t] - v;  // exclusive
}

__global__ void scan3_kernel(const int* __restrict__ counts, const int* __restrict__ blkoff,
                             int* __restrict__ row_start) {
    __shared__ int s[256];
    int t = threadIdx.x, idx = blockIdx.x * 256 + t;
    int v = (idx < NN) ? counts[idx] : 0;
    s[t] = v; __syncthreads();
    for (int off = 1; off < 256; off <<= 1) {
        int xv = (t >= off) ? s[t - off] : 0;
        __syncthreads();
        s[t] += xv;
        __syncthreads();
    }
    if (idx <= NN) row_start[idx] = s[t] - v + blkoff[blockIdx.x];
}

__global__ void fill_kernel(const int* __restrict__ rowi, const int* __restrict__ coli,
                            const int* __restrict__ row_start, int* __restrict__ cursor,
                            int2* __restrict__ perm) {
    int e = blockIdx.x * 256 + threadIdx.x;
    if (e >= NE) return;
    int r = rowi[e];
    int p = row_start[r] + atomicAdd(&cursor[r], 1);
    perm[p] = make_int2(coli[e], r);
}

// ---------------------------------------------------------------------------
// Edge MLP via MFMA over CSR-ordered edges (row gathers ~cache-hits).
// 16 edges per wave-iter; writes v12[p] = (v1,v2) at CSR position.
// ---------------------------------------------------------------------------
__global__ __launch_bounds__(256) void edge_mlp_mfma(
    const __bf16* __restrict__ x, const int2* __restrict__ perm,
    const __bf16* __restrict__ fragbuf,
    const float* __restrict__ b1a, const float* __restrict__ w2a, const float* __restrict__ b2a,
    const float* __restrict__ b1b, const float* __restrict__ w2b, const float* __restrict__ b2b,
    float2* __restrict__ v12)
{
    int lane = threadIdx.x & 63;
    int gwave = (blockIdx.x * 256 + threadIdx.x) >> 6;
    int nwaves = (gridDim.x * 256) >> 6;

    bf16x8 bfrag[4][4];
    const bf16x8* fb = (const bf16x8*)fragbuf;
#pragma unroll
    for (int kt = 0; kt < 4; kt++)
#pragma unroll
        for (int ct = 0; ct < 4; ct++)
            bfrag[kt][ct] = fb[(kt * 4 + ct) * 64 + lane];

    int n = lane & 15;
    int kb = lane >> 4;
    float b1c[4], w2c[4];
#pragma unroll
    for (int ct = 0; ct < 4; ct++) {
        int c = ct * 16 + n;
        b1c[ct] = (c < 32) ? b1a[c] : b1b[c - 32];
        w2c[ct] = (c < 32) ? w2a[c] : w2b[c - 32];
    }
    float bias2a = b2a[0], bias2b = b2b[0];

    const int ngroups = NE / 16;
    for (int g = gwave; g < ngroups; g += nwaves) {
        int2 pe = perm[g * 16 + n];
        const __bf16* xr = x + (size_t)pe.y * FIN + kb * 8;
        const __bf16* xc = x + (size_t)pe.x * FIN + kb * 8;
        f32x4 acc[4] = {{0.f, 0.f, 0.f, 0.f}, {0.f, 0.f, 0.f, 0.f},
                        {0.f, 0.f, 0.f, 0.f}, {0.f, 0.f, 0.f, 0.f}};
#pragma unroll
        for (int kt = 0; kt < 4; kt++) {
            bf16x8 a = *(const bf16x8*)(xr + kt * 32);
            bf16x8 c = *(const bf16x8*)(xc + kt * 32);
            bf16x8 af;
#pragma unroll
            for (int i = 0; i < 8; i++)
                af[i] = (__bf16)fabsf((float)a[i] - (float)c[i]);
#pragma unroll
            for (int ct = 0; ct < 4; ct++)
                acc[ct] = __builtin_amdgcn_mfma_f32_16x16x32_bf16(af, bfrag[kt][ct], acc[ct], 0, 0, 0);
        }
        float p1[4], p2[4];
#pragma unroll
        for (int r = 0; r < 4; r++) {
            float h0 = fmaxf(acc[0][r] + b1c[0], 0.f) * w2c[0];
            float h1 = fmaxf(acc[1][r] + b1c[1], 0.f) * w2c[1];
            float h2 = fmaxf(acc[2][r] + b1c[2], 0.f) * w2c[2];
            float h3 = fmaxf(acc[3][r] + b1c[3], 0.f) * w2c[3];
            p1[r] = h0 + h1;
            p2[r] = h2 + h3;
        }
#pragma unroll
        for (int off = 1; off < 16; off <<= 1)
#pragma unroll
            for (int r = 0; r < 4; r++) {
                p1[r] += __shfl_xor(p1[r], off, 64);
                p2[r] += __shfl_xor(p2[r], off, 64);
            }
        if (n == 0) {
#pragma unroll
            for (int r = 0; r < 4; r++) {
                int p = g * 16 + kb * 4 + r;
                v12[p] = make_float2(1.f / (1.f + expf(-(p1[r] + bias2a))),
                                     1.f / (1.f + expf(-(p2[r] + bias2b))));
            }
        }
    }
}

// ---------------------------------------------------------------------------
// spmm: one wave per node; 4x-unrolled gather loop (4 row-loads in flight).
// ---------------------------------------------------------------------------
__global__ __launch_bounds__(256) void spmm1_kernel(
    const __bf16* __restrict__ x, const int2* __restrict__ perm,
    const float2* __restrict__ v12, const int* __restrict__ row_start,
    __bf16* __restrict__ agg)
{
    int lane = threadIdx.x & 63;
    int i = blockIdx.x * 4 + (threadIdx.x >> 6);
    if (i >= NN) return;
    int f0 = lane * 2;
    float a1x = 0, a1y = 0, a2x = 0, a2y = 0;
    int p0 = row_start[i], p1 = row_start[i + 1];
    int p = p0;
    for (; p + 4 <= p1; p += 4) {
        int cc[4]; float2 vv[4]; bf16x2 ff[4];
#pragma unroll
        for (int u = 0; u < 4; u++) { cc[u] = perm[p + u].x; vv[u] = v12[p + u]; }
#pragma unroll
        for (int u = 0; u < 4; u++)
            ff[u] = *(const bf16x2*)(x + (size_t)cc[u] * FIN + f0);
#pragma unroll
        for (int u = 0; u < 4; u++) {
            float fx = (float)ff[u][0], fy = (float)ff[u][1];
            a1x += vv[u].x * fx; a1y += vv[u].x * fy;
            a2x += vv[u].y * fx; a2y += vv[u].y * fy;
        }
    }
    for (; p < p1; p++) {
        int c = perm[p].x;
        float2 vv = v12[p];
        bf16x2 f = *(const bf16x2*)(x + (size_t)c * FIN + f0);
        float fx = (float)f[0], fy = (float)f[1];
        a1x += vv.x * fx; a1y += vv.x * fy;
        a2x += vv.y * fx; a2y += vv.y * fy;
    }
    __bf16* ag = agg + (size_t)i * 256;
    *(bf16x2*)(ag + f0) = (bf16x2){(__bf16)a1x, (__bf16)a1y};
    *(bf16x2*)(ag + FIN + f0) = (bf16x2){(__bf16)a2x, (__bf16)a2y};
}

__global__ __launch_bounds__(256) void spmm2_kernel(
    const __bf16* __restrict__ h, const int2* __restrict__ perm,
    const float2* __restrict__ v12, const int* __restrict__ row_start,
    __bf16* __restrict__ agg)
{
    int lane = threadIdx.x & 63;
    int i = blockIdx.x * 4 + (threadIdx.x >> 6);
    if (i >= NN) return;
    int f0 = lane * 4;
    float s1x = 0, s1y = 0, s1z = 0, s1w = 0, s2x = 0, s2y = 0, s2z = 0, s2w = 0;
    int p0 = row_start[i], p1 = row_start[i + 1];
    int p = p0;
    for (; p + 4 <= p1; p += 4) {
        int cc[4]; float2 vv[4]; bf16x4 ff[4];
#pragma unroll
        for (int u = 0; u < 4; u++) { cc[u] = perm[p + u].x; vv[u] = v12[p + u]; }
#pragma unroll
        for (int u = 0; u < 4; u++)
            ff[u] = *(const bf16x4*)(h + (size_t)cc[u] * FOUT + f0);
#pragma unroll
        for (int u = 0; u < 4; u++) {
            float fx = (float)ff[u][0], fy = (float)ff[u][1];
            float fz = (float)ff[u][2], fw = (float)ff[u][3];
            s1x += vv[u].x * fx; s1y += vv[u].x * fy; s1z += vv[u].x * fz; s1w += vv[u].x * fw;
            s2x += vv[u].y * fx; s2y += vv[u].y * fy; s2z += vv[u].y * fz; s2w += vv[u].y * fw;
        }
    }
    for (; p < p1; p++) {
        int c = perm[p].x;
        float2 vv = v12[p];
        bf16x4 f = *(const bf16x4*)(h + (size_t)c * FOUT + f0);
        float fx = (float)f[0], fy = (float)f[1], fz = (float)f[2], fw = (float)f[3];
        s1x += vv.x * fx; s1y += vv.x * fy; s1z += vv.x * fz; s1w += vv.x * fw;
        s2x += vv.y * fx; s2y += vv.y * fy; s2z += vv.y * fz; s2w += vv.y * fw;
    }
    __bf16* ag = agg + (size_t)i * 512;
    *(bf16x4*)(ag + f0) = (bf16x4){(__bf16)s1x, (__bf16)s1y, (__bf16)s1z, (__bf16)s1w};
    *(bf16x4*)(ag + FOUT + f0) = (bf16x4){(__bf16)s2x, (__bf16)s2y, (__bf16)s2z, (__bf16)s2w};
}

// ---------------------------------------------------------------------------
// Two-piece bf16 MFMA GEMM, double-buffered LDS staging (issue-early /
// write-late: the vmcnt drain lands AFTER compute, hiding B-load latency).
//   C = [wid ⊙] (A2[M,K2] @ B2) [+ A1[M,K1] @ B1] (+bias) (+BN col stats)
// Grid (ceil(M/128), 2); 4 waves; wave = 32 rows x 128 cols; C bf16.
// ---------------------------------------------------------------------------
#define GBM 128

__device__ __forceinline__ void gemm_stage_regs(
    const __bf16* __restrict__ Bfrag, int kc, int bn, int t, bf16x8 (&stg)[4])
{
#pragma unroll
    for (int it = 0; it < 4; it++) {
        int o = it * 2048 + t * 8;
        int p = o >> 12, j = (o >> 9) & 7, rem = o & 511;
        stg[it] = *(const bf16x8*)(Bfrag + (((kc * 2 + p) * 16 + 8 * bn + j) * 512 + rem));
    }
}

__device__ __forceinline__ void gemm_phase(
    const __bf16* __restrict__ A, const __bf16* __restrict__ Bfrag, int K,
    int bn, int t, int lane, int r0, int r1,
    f32x4 (&acc)[2][8], __bf16* bs)
{
    const __bf16* ap0 = A + (size_t)r0 * K + (lane >> 4) * 8;
    const __bf16* ap1 = A + (size_t)r1 * K + (lane >> 4) * 8;
    int nc = K >> 6;
    bf16x8 stg[4];
    __syncthreads();  // bs safe to overwrite (prior phase/iteration readers done)
    gemm_stage_regs(Bfrag, 0, bn, t, stg);
#pragma unroll
    for (int it = 0; it < 4; it++)
        *(bf16x8*)&bs[it * 2048 + t * 8] = stg[it];
    __syncthreads();
    for (int kc = 0; kc < nc; kc++) {
        __bf16* bcur = bs + (kc & 1) * 8192;
        __bf16* bnx  = bs + ((kc + 1) & 1) * 8192;
        bool more = (kc + 1 < nc);
        if (more) gemm_stage_regs(Bfrag, kc + 1, bn, t, stg);  // in flight across compute
        bf16x8 a00 = *(const bf16x8*)(ap0 + kc * 64);
        bf16x8 a10 = *(const bf16x8*)(ap1 + kc * 64);
        bf16x8 a01 = *(const bf16x8*)(ap0 + kc * 64 + 32);
        bf16x8 a11 = *(const bf16x8*)(ap1 + kc * 64 + 32);
#pragma unroll
        for (int ct = 0; ct < 8; ct++) {
            bf16x8 bf0 = *(const bf16x8*)&bcur[ct * 512 + lane * 8];
            acc[0][ct] = __builtin_amdgcn_mfma_f32_16x16x32_bf16(a00, bf0, acc[0][ct], 0, 0, 0);
            acc[1][ct] = __builtin_amdgcn_mfma_f32_16x16x32_bf16(a10, bf0, acc[1][ct], 0, 0, 0);
            bf16x8 bf1 = *(const bf16x8*)&bcur[4096 + ct * 512 + lane * 8];
            acc[0][ct] = __builtin_amdgcn_mfma_f32_16x16x32_bf16(a01, bf1, acc[0][ct], 0, 0, 0);
            acc[1][ct] = __builtin_amdgcn_mfma_f32_16x16x32_bf16(a11, bf1, acc[1][ct], 0, 0, 0);
        }
        if (more) {
            __syncthreads();  // all waves done reading bnx's old content
#pragma unroll
            for (int it = 0; it < 4; it++)
                *(bf16x8*)&bnx[it * 2048 + t * 8] = stg[it];
            __syncthreads();  // bnx visible for next iteration
        }
    }
}

__global__ __launch_bounds__(256) void gemm_mfma(
    const __bf16* __restrict__ A2, const __bf16* __restrict__ B2frag, int K2,
    const float* __restrict__ wid,
    const __bf16* __restrict__ A1, const __bf16* __restrict__ B1frag, int K1,
    const float* __restrict__ bias, __bf16* __restrict__ C, int M,
    float* __restrict__ colsum, float* __restrict__ colsq)
{
    __shared__ __bf16 bs[16384];    // 2 x 16KB double buffer
    __shared__ float lsum[128], lsq[128];
    int t = threadIdx.x, lane = t & 63, w = t >> 6;
    int bn = blockIdx.y;
    int n = lane & 15, kb = lane >> 4;
    int rowbase = blockIdx.x * GBM + w * 32;
    int r0 = rowbase + n;      if (r0 > M - 1) r0 = M - 1;
    int r1 = rowbase + 16 + n; if (r1 > M - 1) r1 = M - 1;

    f32x4 acc[2][8];
#pragma unroll
    for (int rf = 0; rf < 2; rf++)
#pragma unroll
        for (int ct = 0; ct < 8; ct++) acc[rf][ct] = (f32x4){0.f, 0.f, 0.f, 0.f};

    gemm_phase(A2, B2frag, K2, bn, t, lane, r0, r1, acc, bs);

    if (wid) {
#pragma unroll
        for (int rf = 0; rf < 2; rf++) {
            int rb = rowbase + rf * 16 + kb * 4;
            float w4[4];
#pragma unroll
            for (int r = 0; r < 4; r++) {
                int gm = rb + r; if (gm > M - 1) gm = M - 1;
                w4[r] = wid[gm];
            }
#pragma unroll
            for (int ct = 0; ct < 8; ct++)
#pragma unroll
                for (int r = 0; r < 4; r++) acc[rf][ct][r] *= w4[r];
        }
    }

    if (A1) gemm_phase(A1, B1frag, K1, bn, t, lane, r0, r1, acc, bs);

    // ---- epilogue: bias, store bf16, BN stats ----
    bool dostats = (colsum != nullptr);
    if (dostats) {
        if (t < 128) { lsum[t] = 0.f; lsq[t] = 0.f; }
        __syncthreads();
    }
#pragma unroll
    for (int rf = 0; rf < 2; rf++) {
        int rbase = rowbase + rf * 16 + kb * 4;
#pragma unroll
        for (int ct = 0; ct < 8; ct++) {
            int col = bn * 128 + ct * 16 + n;
            float bv = bias ? bias[col] : 0.f;
            float ps = 0.f, pq = 0.f;
#pragma unroll
            for (int r = 0; r < 4; r++) {
                int gm = rbase + r;
                if (gm < M) {
                    float v = acc[rf][ct][r] + bv;
                    C[(size_t)gm * 256 + col] = (__bf16)v;
                    ps += v; pq += v * v;
                }
            }
            if (dostats) {
                ps += __shfl_xor(ps, 16, 64); pq += __shfl_xor(pq, 16, 64);
                ps += __shfl_xor(ps, 32, 64); pq += __shfl_xor(pq, 32, 64);
                if (lane < 16) {
                    atomicAdd(&lsum[ct * 16 + n], ps);
                    atomicAdd(&lsq[ct * 16 + n], pq);
                }
            }
        }
    }
    if (dostats) {
        __syncthreads();
        if (t < 128) {
            atomicAdd(&colsum[bn * 128 + t], lsum[t]);
            atomicAdd(&colsq[bn * 128 + t], lsq[t]);
        }
    }
}

// ---------------------------------------------------------------------------
// BN apply (+relu) bf16->bf16, and final BN+residual+relu bf16->fp32.
// ---------------------------------------------------------------------------
__device__ __forceinline__ float bn1c(float v, float s, float q, float g, float b) {
    const float invn = 1.0f / (float)NN;
    float mu = s * invn;
    float var = q * invn - mu * mu;
    float r = rsqrtf(var + EPSF);
    return (v - mu) * r * g + b;
}

__global__ __launch_bounds__(256) void bn_relu_kernel(
    const __bf16* __restrict__ h, const float* __restrict__ stats,
    const float* __restrict__ g, const float* __restrict__ b, __bf16* __restrict__ o)
{
    size_t idx = (size_t)blockIdx.x * 256 + threadIdx.x;
    int j = ((int)idx & 31) * 8;
    bf16x8 v = ((const bf16x8*)h)[idx];
    bf16x8 r;
#pragma unroll
    for (int u = 0; u < 8; u++)
        r[u] = (__bf16)fmaxf(bn1c((float)v[u], stats[j + u], stats[256 + j + u], g[j + u], b[j + u]), 0.f);
    ((bf16x8*)o)[idx] = r;
}

__global__ __launch_bounds__(256) void final_kernel(
    const __bf16* __restrict__ h2, const float* __restrict__ stats,
    const float* __restrict__ g, const float* __restrict__ b,
    const __bf16* __restrict__ resb, float* __restrict__ o)
{
    size_t idx = (size_t)blockIdx.x * 256 + threadIdx.x;
    int j = ((int)idx & 31) * 8;
    bf16x8 v = ((const bf16x8*)h2)[idx];
    bf16x8 rr = ((const bf16x8*)resb)[idx];
    float r[8];
#pragma unroll
    for (int u = 0; u < 8; u++)
        r[u] = fmaxf(bn1c((float)v[u], stats[j + u], stats[256 + j + u], g[j + u], b[j + u]) + (float)rr[u], 0.f);
    float4 o0 = {r[0], r[1], r[2], r[3]}, o1 = {r[4], r[5], r[6], r[7]};
    ((float4*)o)[idx * 2 + 0] = o0;
    ((float4*)o)[idx * 2 + 1] = o1;
}

// ---------------------------------------------------------------------------
extern "C" void kernel_launch(void* const* d_in, const int* in_sizes, int n_in,
                              void* d_out, int out_size, void* d_ws, size_t ws_size,
                              hipStream_t stream)
{
    (void)in_sizes; (void)n_in; (void)out_size; (void)ws_size;
    const float* x    = (const float*)d_in[0];
    const float* wid  = (const float*)d_in[1];
    const int*   widx = (const int*)d_in[2];
    const float* m1w1 = (const float*)d_in[4];
    const float* m1b1 = (const float*)d_in[5];
    const float* m1w2 = (const float*)d_in[6];
    const float* m1b2 = (const float*)d_in[7];
    const float* m2w1 = (const float*)d_in[8];
    const float* m2b1 = (const float*)d_in[9];
    const float* m2w2 = (const float*)d_in[10];
    const float* m2b2 = (const float*)d_in[11];
    const float* fc1w = (const float*)d_in[12];
    const float* fc1b = (const float*)d_in[13];
    const float* bn1g = (const float*)d_in[14];
    const float* bn1b = (const float*)d_in[15];
    const float* fc2w = (const float*)d_in[16];
    const float* fc2b = (const float*)d_in[17];
    const float* bn2g = (const float*)d_in[18];
    const float* bn2b = (const float*)d_in[19];
    const float* resw = (const float*)d_in[20];
    float* out = (float*)d_out;

    char* ws = (char*)d_ws;
    __bf16* xbf   = (__bf16*)(ws);                    // 12.8 MB
    int2*   perm  = (int2*)(ws + 12800000);           // 6.4 MB
    float2* v12   = (float2*)(ws + 19200000);         // 6.4 MB
    __bf16* agg1s = (__bf16*)(ws + 25600000);         // [NN,256] 25.6 MB
    __bf16* agg2s = (__bf16*)(ws + 51200000);         // [NN,512] 51.2 MB
    __bf16* h1    = (__bf16*)(ws + 102400000);        // 25.6 MB (h2 overlay)
    __bf16* h2    = h1;
    __bf16* hbn   = (__bf16*)(ws + 128000000);        // 25.6 MB
    __bf16* resb  = (__bf16*)(ws + 153600000);        // 25.6 MB
    const size_t offS = 179200000;
    int* row_start = (int*)(ws + offS);               // 200064 B
    int* cursor    = (int*)(ws + offS + 200064);      // 200064 B
    int* blksum    = (int*)(ws + offS + 400128);
    int* blkoff    = (int*)(ws + offS + 401152);
    float* stats   = (float*)(ws + offS + 402176);    // 1024 floats
    __bf16* efrag    = (__bf16*)(ws + offS + 406272);   // 16 KB
    __bf16* bfrag1a  = (__bf16*)(ws + offS + 422656);   // 128*256*2 = 64 KB
    __bf16* bfrag1bc = (__bf16*)(ws + offS + 488192);   // 256*256*2 = 128 KB
    __bf16* bfrag2a  = (__bf16*)(ws + offS + 619264);   // 256*256*2 = 128 KB
    __bf16* bfrag2bc = (__bf16*)(ws + offS + 750336);   // 512*256*2 = 256 KB
    __bf16* bfragR   = (__bf16*)(ws + offS + 1012480);  // 128*256*2 = 64 KB

    dim3 b256(256);
    dim3 ggrid((NN + GBM - 1) / GBM, 2);

    // 0) conversions / weight packing
    cvt_bf16_kernel<<<3125, b256, 0, stream>>>(x, xbf, NN * FIN / 8);
    prep_w_kernel<<<32, b256, 0, stream>>>(m1w1, m2w1, efrag);
    prep_b_kernel<<<128, b256, 0, stream>>>(fc1w, bfrag1a, 128);
    prep_b_kernel<<<256, b256, 0, stream>>>(fc1w + 128 * 256, bfrag1bc, 256);
    prep_b_kernel<<<256, b256, 0, stream>>>(fc2w, bfrag2a, 256);
    prep_b_kernel<<<512, b256, 0, stream>>>(fc2w + 256 * 256, bfrag2bc, 512);
    prep_b_kernel<<<128, b256, 0, stream>>>(resw, bfragR, 128);

    // 1) CSR build (indices only)
    hipMemsetAsync(cursor, 0, NN * 4, stream);
    hist_kernel<<<NE / 256, b256, 0, stream>>>(widx, cursor);
    scan1_kernel<<<NCHUNK, b256, 0, stream>>>(cursor, blksum);
    scan2_kernel<<<1, b256, 0, stream>>>(blksum, blkoff);
    scan3_kernel<<<NCHUNK, b256, 0, stream>>>(cursor, blkoff, row_start);
    hipMemsetAsync(cursor, 0, NN * 4, stream);
    fill_kernel<<<NE / 256, b256, 0, stream>>>(widx, widx + NE, row_start, cursor, perm);

    // 2) edge MLP over CSR order -> v12
    edge_mlp_mfma<<<1024, b256, 0, stream>>>(xbf, perm, efrag,
        m1b1, m1w2, m1b2, m2b1, m2w2, m2b2, v12);

    // 3) conv1
    spmm1_kernel<<<NN / 4, b256, 0, stream>>>(xbf, perm, v12, row_start, agg1s);
    hipMemsetAsync(stats, 0, 1024 * 4, stream);
    gemm_mfma<<<ggrid, b256, 0, stream>>>(xbf, bfrag1a, 128, wid,
        agg1s, bfrag1bc, 256, fc1b, h1, NN, stats, stats + 256);
    bn_relu_kernel<<<NN * FOUT / 8 / 256, b256, 0, stream>>>(h1, stats, bn1g, bn1b, hbn);

    // 4) conv2 + residual
    spmm2_kernel<<<NN / 4, b256, 0, stream>>>(hbn, perm, v12, row_start, agg2s);
    gemm_mfma<<<ggrid, b256, 0, stream>>>(hbn, bfrag2a, 256, wid,
        agg2s, bfrag2bc, 512, fc2b, h2, NN, stats + 512, stats + 768);
    gemm_mfma<<<ggrid, b256, 0, stream>>>(xbf, bfragR, 128, nullptr,
        nullptr, nullptr, 0, nullptr, resb, NN, nullptr, nullptr);
    final_kernel<<<NN * FOUT / 8 / 256, b256, 0, stream>>>(h2, stats + 512, bn2g, bn2b, resb, out);
}